// Round 7
// baseline (151.781 us; speedup 1.0000x reference)
//
#include <hip/hip_runtime.h>
#include <hip/hip_bf16.h>

// Problem constants
constexpr int cB = 4;
constexpr int cN = 4096;
constexpr int cD = 512;
constexpr int cK = 64;
constexpr int cNB = cB * cN;       // 16384 rows
constexpr int cNP = cN + 1;        // 4097 prefix rows
constexpr int cCS = 16;            // chunk size for scans
constexpr int cNC = cN / cCS;      // 256 chunks per batch
constexpr int cNC1 = cNC + 1;      // 257

typedef unsigned short u16;
typedef unsigned int u32;
typedef unsigned long long u64;
typedef __bf16 bf16x8 __attribute__((ext_vector_type(8)));
typedef float f32x4 __attribute__((ext_vector_type(4)));

// ---- workspace layout (in floats) ----
constexpr size_t OFF_H    = 0;                                  // cNB*cK
constexpr size_t OFF_T1   = OFF_H    + (size_t)cNB * cK;        // cNB
constexpr size_t OFF_T2   = OFF_T1   + cNB;                     // cNB
constexpr size_t OFF_T2S  = OFF_T2   + cNB;                     // cNB (sorted)
constexpr size_t OFF_IDX  = OFF_T2S  + cNB;                     // cNB (int)
constexpr size_t OFF_P    = OFF_IDX  + cNB;                     // cNB (int) split point per row
constexpr size_t OFF_KEYS = OFF_P    + cNB;                     // cNB u64 = 2*cNB floats
constexpr size_t OFF_EPL  = OFF_KEYS + (size_t)cNB * 2;         // cB*cNP*cK
constexpr size_t OFF_GNL  = OFF_EPL  + (size_t)cB * cNP * cK;   // cB*cNP*cK
constexpr size_t OFF_EPS  = OFF_GNL  + (size_t)cB * cNP * cK;   // cB*cNP
constexpr size_t OFF_GNS  = OFF_EPS  + (size_t)cB * cNP;        // cB*cNP
constexpr size_t OFF_CHE  = OFF_GNS  + (size_t)cB * cNP;        // cB*cNC*cK
constexpr size_t OFF_CHG  = OFF_CHE  + (size_t)cB * cNC * cK;
constexpr size_t OFF_CHES = OFF_CHG  + (size_t)cB * cNC * cK;   // cB*cNC
constexpr size_t OFF_CHGS = OFF_CHES + (size_t)cB * cNC;
constexpr size_t OFF_OFE  = OFF_CHGS + (size_t)cB * cNC;        // cB*cNC1*cK (fallback only)
constexpr size_t OFF_OFG  = OFF_OFE  + (size_t)cB * cNC1 * cK;
constexpr size_t OFF_OFES = OFF_OFG  + (size_t)cB * cNC1 * cK;  // cB*cNC1
constexpr size_t OFF_OFGS = OFF_OFES + (size_t)cB * cNC1;
constexpr size_t OFF_WB16 = OFF_OFGS + (size_t)cB * cNC1;       // cK*cD u16

__device__ __forceinline__ u16 f2bf(float f) {
    unsigned u = __float_as_uint(f);
    u += 0x7fffu + ((u >> 16) & 1u);   // RNE
    return (u16)(u >> 16);
}
__device__ __forceinline__ u32 pk2(float a, float b) {
    return (u32)f2bf(a) | ((u32)f2bf(b) << 16);
}
// monotone float -> sortable uint (ascending)
__device__ __forceinline__ u32 f2sort(float f) {
    u32 b = __float_as_uint(f);
    u32 mask = (u32)((int)b >> 31);
    return b ^ (mask | 0x80000000u);
}

// ---------------------------------------------------------------------------
// k_prep (544 blocks): blocks <512: one pass over x -> exact f32 t1/t2 via
// in-block fold of Wa with Wb/Wc; lane 0 also emits the composite sort key
// keysG[row] = f2sort(t2)<<32 | rowInBatch (consumed scalar-side by rank).
// Blocks >=512: Wa -> wab16 (bf16 B operand).
// ---------------------------------------------------------------------------
__global__ __launch_bounds__(256) void k_prep(
    const float* __restrict__ x, const float* __restrict__ Wa,
    const float* __restrict__ Wb, const float* __restrict__ wbb,
    const float* __restrict__ Wc, const float* __restrict__ wcb,
    u16* __restrict__ wab16, float* __restrict__ t1, float* __restrict__ t2,
    u64* __restrict__ keysG)
{
    __shared__ float wabL[cD], wacL[cD];
    int t = threadIdx.x;
    if (blockIdx.x >= 512) {           // wprep slice: 32 blocks x 256 x 4 elems
        int i4 = (((int)blockIdx.x - 512) * 256 + t) * 4;
        float4 v = *(const float4*)(Wa + i4);
        uint2 p = {pk2(v.x, v.y), pk2(v.z, v.w)};
        *(uint2*)(wab16 + i4) = p;
        return;
    }
    float s1a = 0.f, s2a = 0.f, s1b = 0.f, s2b = 0.f;
#pragma unroll 8
    for (int k = 0; k < cK; ++k) {
        float wbk = Wb[k], wck = Wc[k];
        float wa1 = Wa[k * cD + t];
        float wa2 = Wa[k * cD + t + 256];
        s1a += wa1 * wbk; s2a += wa1 * wck;
        s1b += wa2 * wbk; s2b += wa2 * wck;
    }
    wabL[t] = s1a; wacL[t] = s2a; wabL[t + 256] = s1b; wacL[t + 256] = s2b;
    __syncthreads();

    int w = t >> 6, lane = t & 63;
    int d1 = lane * 4, d2 = 256 + lane * 4;
    float4 wbA = *(const float4*)&wabL[d1], wbB = *(const float4*)&wabL[d2];
    float4 wcA = *(const float4*)&wacL[d1], wcB = *(const float4*)&wacL[d2];
    float wbbv = wbb[0], wcbv = wcb[0];
#pragma unroll 2
    for (int rr = 0; rr < 8; ++rr) {
        int row = blockIdx.x * 32 + w * 8 + rr;
        const float* xp = x + (size_t)row * cD;
        float4 a  = *(const float4*)(xp + d1);
        float4 bq = *(const float4*)(xp + d2);
        float p1 = a.x*wbA.x + a.y*wbA.y + a.z*wbA.z + a.w*wbA.w
                 + bq.x*wbB.x + bq.y*wbB.y + bq.z*wbB.z + bq.w*wbB.w;
        float p2 = a.x*wcA.x + a.y*wcA.y + a.z*wcA.z + a.w*wcA.w
                 + bq.x*wcB.x + bq.y*wcB.y + bq.z*wcB.z + bq.w*wcB.w;
#pragma unroll
        for (int off = 32; off > 0; off >>= 1) {
            p1 += __shfl_down(p1, off, 64);
            p2 += __shfl_down(p2, off, 64);
        }
        if (lane == 0) {
            t1[row] = p1 + wbbv;
            float t2v = p2 + wcbv;
            t2[row] = t2v;
            keysG[row] = ((u64)f2sort(t2v) << 32) | (u32)(row & (cN - 1));
        }
    }
}

// ---------------------------------------------------------------------------
// k_projrank (512 blocks): blocks <256 do the bf16-MFMA GEMM tile (64 rows)
// with direct global->register fragments (zero LDS, zero barriers).
// Blocks >=256: rank + split-point via SCALAR key stream: the key array is
// wave-uniform (all 64 lanes compare the same key against per-lane
// thresholds), so reading keysG with a readfirstlane-uniform base turns the
// inner loop into s_load_dwordx16 + pure VALU compares on 4 parallel SIMDs
// -- replacing 4096 serialized LDS-pipe broadcast issues per CU (~24.6K cyc)
// with ~8K VALU cyc/SIMD. Only 2 KB LDS (partials) remains.
// ---------------------------------------------------------------------------
__global__ __launch_bounds__(256) void k_projrank(
    const float* __restrict__ x, const u16* __restrict__ wab16,
    const float* __restrict__ t1, const float* __restrict__ t2,
    const u64* __restrict__ keysG,
    float* __restrict__ h, float* __restrict__ t2s, int* __restrict__ idxs,
    int* __restrict__ pidx)
{
    __shared__ int part[512];          // rank partials (2 KB)
    int t = threadIdx.x;
    if (blockIdx.x < 256) {
        int rowbase = blockIdx.x * 64;
        int w = t >> 6, lane = t & 63, m = lane & 15, quad = lane >> 4;
        const float* xg = x + (size_t)(rowbase + w * 16 + m) * cD + quad * 8;
        const u16* wg = wab16 + (size_t)m * cD + quad * 8;

        f32x4 acc[4] = {{0.f,0.f,0.f,0.f},{0.f,0.f,0.f,0.f},
                        {0.f,0.f,0.f,0.f},{0.f,0.f,0.f,0.f}};
#pragma unroll 4
        for (int s = 0; s < 16; ++s) {
            float4 xa  = *(const float4*)(xg + s * 32);
            float4 xb2 = *(const float4*)(xg + s * 32 + 4);
            uint4 xv = {pk2(xa.x, xa.y), pk2(xa.z, xa.w),
                        pk2(xb2.x, xb2.y), pk2(xb2.z, xb2.w)};
            bf16x8 av;
            __builtin_memcpy(&av, &xv, 16);
#pragma unroll
            for (int g = 0; g < 4; ++g) {
                uint4 wv = *(const uint4*)(wg + (size_t)g * 16 * cD + s * 32);
                bf16x8 bv;
                __builtin_memcpy(&bv, &wv, 16);
                acc[g] = __builtin_amdgcn_mfma_f32_16x16x32_bf16(av, bv, acc[g], 0, 0, 0);
            }
        }
#pragma unroll
        for (int g = 0; g < 4; ++g) {
#pragma unroll
            for (int r4 = 0; r4 < 4; ++r4) {
                int row = w * 16 + quad * 4 + r4;
                h[(size_t)(rowbase + row) * cK + g * 16 + m] = acc[g][r4];
            }
        }
    } else {
        int rb = blockIdx.x - 256;
        int b = rb >> 6;
        int rowgrp = rb & 63;
        int lane = t & 63, subset = t >> 6;
        int myrow = rowgrp * 64 + lane;
        const u64* kb = keysG + (size_t)b * cN;
        u64 mykey = kb[myrow];                             // per-lane threshold
        u32 pk_hi = f2sort(-t1[(size_t)b * cN + myrow]);   // p-threshold hi word
        // wave-uniform base -> scalar loads for the key stream
        int s0 = __builtin_amdgcn_readfirstlane(subset) * 1024;
        int cnt = 0, cnt2 = 0;
#pragma unroll 8
        for (int kk = 0; kk < 1024; ++kk) {
            u64 kv = kb[s0 + kk];
            cnt  += (kv < mykey) ? 1 : 0;
            cnt2 += ((u32)(kv >> 32) < pk_hi) ? 1 : 0;
        }
        part[subset * 64 + lane] = cnt;
        part[256 + subset * 64 + lane] = cnt2;
        __syncthreads();
        if (t < 64) {
            int jj = rowgrp * 64 + t;
            int rank = part[t] + part[64 + t] + part[128 + t] + part[192 + t];
            int pc   = part[256 + t] + part[320 + t] + part[384 + t] + part[448 + t];
            t2s[b * cN + rank] = t2[b * cN + jj];
            idxs[b * cN + rank] = jj;
            pidx[b * cN + jj] = pc;
        }
    }
}

// ---------------------------------------------------------------------------
// k_chunkscan: 1024 blocks x 128 thr per (batch, chunk-of-16). The 16 h-rows
// are gathered ONCE into 4 KB LDS (wave w loads rows w*8..w*8+8); wave 0
// then does the E (suffix) scan, wave 1 the G (prefix) scan.
// ---------------------------------------------------------------------------
__global__ __launch_bounds__(128) void k_chunkscan(
    const float* __restrict__ t2s, const int* __restrict__ idxs,
    const float* __restrict__ h,
    float* __restrict__ EpL, float* __restrict__ GnL,
    float* __restrict__ eps_l, float* __restrict__ gns_l,
    float* __restrict__ chE, float* __restrict__ chG,
    float* __restrict__ chEs, float* __restrict__ chGs)
{
    __shared__ float hs[cCS][cK];      // 4 KB
    int t = threadIdx.x;
    int lane = t & 63, w = t >> 6;     // w in {0,1}
    int unit = blockIdx.x;
    int c = unit & (cNC - 1);
    int b = unit >> 8;
    int base = b * cN + c * cCS;
    size_t rowbase = ((size_t)b * cNP + c * cCS) * cK;
    int sbase = b * cNP + c * cCS;
    float M2 = t2s[b * cN + cN - 1];
    int   idxv = (lane < 8) ? idxs[base + w * 8 + lane] : 0;
    float t2v  = (lane < cCS) ? t2s[base + lane] : 0.f;

    // each wave gathers 8 h-rows into LDS
#pragma unroll
    for (int ii = 0; ii < 8; ++ii) {
        int j = __shfl(idxv, ii, 64);
        hs[w * 8 + ii][lane] = h[((size_t)b * cN + j) * cK + lane];
    }
    float slope = w ? 0.2f : 1.0f;
    float ev[cCS];
#pragma unroll
    for (int i = 0; i < cCS; ++i)
        ev[i] = __expf(slope * (__shfl(t2v, i, 64) - M2));
    __syncthreads();

    if (w == 0) {
        if (c == cNC - 1) {
            EpL[((size_t)b * cNP + cN) * cK + lane] = 0.f;
            if (lane == 0) eps_l[b * cNP + cN] = 0.f;
        }
        float acc = 0.f, accs = 0.f;
#pragma unroll
        for (int i = cCS - 1; i >= 0; --i) {
            acc += ev[i] * hs[i][lane]; accs += ev[i];
            EpL[rowbase + (size_t)i * cK + lane] = acc;
            if (lane == 0) eps_l[sbase + i] = accs;
        }
        chE[((size_t)b * cNC + c) * cK + lane] = acc;
        if (lane == 0) chEs[b * cNC + c] = accs;
    } else {
        if (c == cNC - 1) {
            GnL[((size_t)b * cNP + cN) * cK + lane] = 0.f;
            if (lane == 0) gns_l[b * cNP + cN] = 0.f;
        }
        float acc = 0.f, accs = 0.f;
#pragma unroll
        for (int i = 0; i < cCS; ++i) {
            GnL[rowbase + (size_t)i * cK + lane] = acc;
            if (lane == 0) gns_l[sbase + i] = accs;
            acc += ev[i] * hs[i][lane]; accs += ev[i];
        }
        chG[((size_t)b * cNC + c) * cK + lane] = acc;
        if (lane == 0) chGs[b * cNC + c] = accs;
    }
}

// ---------------------------------------------------------------------------
// k_outf: 256 blocks x 256 thr x 64 rows. Per-block prelude rebuilds the
// batch's offset tables in 135 KB dynamic LDS from chE/chG (replaces the
// k_offsets kernel + boundary). Main loop: 16 rows/wave, gather + combine.
// ---------------------------------------------------------------------------
constexpr unsigned SMEM_OUT = 134664;
__global__ __launch_bounds__(256, 1) void k_outf(
    const float* __restrict__ t1, const float* __restrict__ t2s,
    const int* __restrict__ pidx,
    const float* __restrict__ EpL, const float* __restrict__ GnL,
    const float* __restrict__ eps_l, const float* __restrict__ gns_l,
    const float* __restrict__ chE, const float* __restrict__ chG,
    const float* __restrict__ chEs, const float* __restrict__ chGs,
    const float* __restrict__ bias, float* __restrict__ out)
{
    extern __shared__ char sm[];
    float (*ofEl)[64] = (float(*)[64])(sm);                 // 257*64
    float (*ofGl)[64] = (float(*)[64])(sm + 65792);         // 257*64
    float* ofEsL      = (float*)(sm + 131584);              // 257
    float* ofGsL      = (float*)(sm + 132612);              // 257
    float (*wsum)[64] = (float(*)[64])(sm + 133640);        // 4*64

    int t = threadIdx.x, lane = t & 63, w = t >> 6;
    int blk = blockIdx.x;
    int b = blk >> 6;
    const float* chEb = chE + (size_t)b * cNC * cK;
    const float* chGb = chG + (size_t)b * cNC * cK;
    int c0 = w * 64;

    // ---- E suffix scan (vector) + scalar scans on waves 0/1 ----
    {
        float cv[64]; float s = 0.f;
#pragma unroll
        for (int i = 0; i < 64; ++i) { cv[i] = chEb[(size_t)(c0 + i) * cK + lane]; s += cv[i]; }
        wsum[w][lane] = s;
        if (w == 0) {
            float e0 = chEs[b*cNC + lane*4+0], e1 = chEs[b*cNC + lane*4+1];
            float e2 = chEs[b*cNC + lane*4+2], e3 = chEs[b*cNC + lane*4+3];
            float p = e0+e1+e2+e3, s2 = p;
#pragma unroll
            for (int off = 1; off < 64; off <<= 1) {
                float tv = __shfl_down(s2, off, 64);
                if (lane + off < 64) s2 += tv;
            }
            float excl = s2 - p;                  // sum over lanes > lane
            ofEsL[lane*4+0] = excl + e1 + e2 + e3;
            ofEsL[lane*4+1] = excl + e2 + e3;
            ofEsL[lane*4+2] = excl + e3;
            ofEsL[lane*4+3] = excl;
            if (lane == 0) ofEsL[cNC] = 0.f;
        } else if (w == 1) {
            float e0 = chGs[b*cNC + lane*4+0], e1 = chGs[b*cNC + lane*4+1];
            float e2 = chGs[b*cNC + lane*4+2], e3 = chGs[b*cNC + lane*4+3];
            float p = e0+e1+e2+e3, s2 = p;
#pragma unroll
            for (int off = 1; off < 64; off <<= 1) {
                float tv = __shfl_up(s2, off, 64);
                if (lane >= off) s2 += tv;
            }
            float excl = s2 - p;                  // sum over lanes < lane
            ofGsL[lane*4+0] = excl;
            ofGsL[lane*4+1] = excl + e0;
            ofGsL[lane*4+2] = excl + e0 + e1;
            ofGsL[lane*4+3] = excl + e0 + e1 + e2;
            if (lane == 63) ofGsL[cNC] = s2;
        }
        __syncthreads();
        float base = 0.f;
        for (int w2 = w + 1; w2 < 4; ++w2) base += wsum[w2][lane];
        float run = base;
#pragma unroll
        for (int i = 63; i >= 0; --i) { ofEl[c0 + i][lane] = run; run += cv[i]; }
        if (w == 0) ofEl[cNC][lane] = 0.f;
    }
    __syncthreads();    // wsum reuse guard (base reads done)
    // ---- G prefix scan (vector) ----
    {
        float cv[64]; float s = 0.f;
#pragma unroll
        for (int i = 0; i < 64; ++i) { cv[i] = chGb[(size_t)(c0 + i) * cK + lane]; s += cv[i]; }
        wsum[w][lane] = s;
        __syncthreads();
        float base = 0.f;
        for (int w2 = 0; w2 < w; ++w2) base += wsum[w2][lane];
        float run = base;
#pragma unroll
        for (int i = 0; i < 64; ++i) { ofGl[c0 + i][lane] = run; run += cv[i]; }
        if (w == 3) ofGl[cNC][lane] = run;
    }
    __syncthreads();

    // ---- main: 64 rows/block, 16 rows/wave ----
    float bv = bias[lane];
    float M2 = t2s[(size_t)b * cN + cN - 1];
    int r0 = blk * 64 + w * 16;
    const float* epsb = eps_l + (size_t)b * cNP;
    const float* gnsb = gns_l + (size_t)b * cNP;
#pragma unroll 8
    for (int i = 0; i < 16; ++i) {
        int r = r0 + i;
        float T1 = t1[r];
        float smax = T1 + M2;
        float m = fmaxf(smax, 0.2f * smax);      // leaky_relu(smax) = row max
        float A  = __expf(smax - m);
        float Cc = __expf(0.2f * smax - m);
        int p = pidx[r];
        int c = p >> 4;
        size_t pr = ((size_t)b * cNP + p) * cK + lane;
        float num = A * (EpL[pr] + ofEl[c][lane]) + Cc * (GnL[pr] + ofGl[c][lane]);
        float den = A * (epsb[p] + ofEsL[c]) + Cc * (gnsb[p] + ofGsL[c]);
        out[(size_t)r * cK + lane] = num / den + bv;
    }
}

// ---------------------------------------------------------------------------
// Fallback pair (only if the 135 KB LDS attribute is unavailable).
// ---------------------------------------------------------------------------
__global__ __launch_bounds__(1024) void k_offsets(
    const float* __restrict__ chE, const float* __restrict__ chG,
    const float* __restrict__ chEs, const float* __restrict__ chGs,
    float* __restrict__ ofE, float* __restrict__ ofG,
    float* __restrict__ ofEs, float* __restrict__ ofGs)
{
    __shared__ float wsum[16][64];
    int t = threadIdx.x;
    int lane = t & 63, w = t >> 6;
    int dir = blockIdx.x & 1;
    int b = blockIdx.x >> 1;
    const float* ch = dir ? chG : chE;
    float* of = dir ? ofG : ofE;
    int c0 = w * 16;

    float cv[16];
    float s = 0.f;
#pragma unroll
    for (int i = 0; i < 16; ++i) {
        cv[i] = ch[((size_t)b * cNC + c0 + i) * cK + lane];
        s += cv[i];
    }
    wsum[w][lane] = s;
    __syncthreads();
    float base = 0.f;
    if (dir == 0) { for (int w2 = w + 1; w2 < 16; ++w2) base += wsum[w2][lane]; }
    else          { for (int w2 = 0; w2 < w; ++w2) base += wsum[w2][lane]; }

    if (dir == 0) {
        float run = base;
#pragma unroll
        for (int i = 15; i >= 0; --i) {
            of[((size_t)b * cNC1 + c0 + i) * cK + lane] = run;
            run += cv[i];
        }
        if (w == 0) of[((size_t)b * cNC1 + cNC) * cK + lane] = 0.f;
    } else {
        float run = base;
#pragma unroll
        for (int i = 0; i < 16; ++i) {
            of[((size_t)b * cNC1 + c0 + i) * cK + lane] = run;
            run += cv[i];
        }
        if (w == 15) of[((size_t)b * cNC1 + cNC) * cK + lane] = run;
    }

    if (w == 0) {
        const float* chs = dir ? chGs : chEs;
        float* ofs = dir ? ofGs : ofEs;
        float e0 = chs[b * cNC + lane * 4 + 0];
        float e1 = chs[b * cNC + lane * 4 + 1];
        float e2 = chs[b * cNC + lane * 4 + 2];
        float e3 = chs[b * cNC + lane * 4 + 3];
        float p = e0 + e1 + e2 + e3;
        if (dir == 0) {
            float s2 = p;
#pragma unroll
            for (int off = 1; off < 64; off <<= 1) {
                float tv = __shfl_down(s2, off, 64);
                if (lane + off < 64) s2 += tv;
            }
            float excl = s2 - p;
            ofs[b * cNC1 + lane * 4 + 0] = excl + e1 + e2 + e3;
            ofs[b * cNC1 + lane * 4 + 1] = excl + e2 + e3;
            ofs[b * cNC1 + lane * 4 + 2] = excl + e3;
            ofs[b * cNC1 + lane * 4 + 3] = excl;
            if (lane == 0) ofs[b * cNC1 + cNC] = 0.f;
        } else {
            float s2 = p;
#pragma unroll
            for (int off = 1; off < 64; off <<= 1) {
                float tv = __shfl_up(s2, off, 64);
                if (lane >= off) s2 += tv;
            }
            float excl = s2 - p;
            ofs[b * cNC1 + lane * 4 + 0] = excl;
            ofs[b * cNC1 + lane * 4 + 1] = excl + e0;
            ofs[b * cNC1 + lane * 4 + 2] = excl + e0 + e1;
            ofs[b * cNC1 + lane * 4 + 3] = excl + e0 + e1 + e2;
            if (lane == 63) ofs[b * cNC1 + cNC] = s2;
        }
    }
}

__global__ __launch_bounds__(256) void k_out(
    const float* __restrict__ t1, const float* __restrict__ t2s,
    const int* __restrict__ pidx,
    const float* __restrict__ EpL, const float* __restrict__ GnL,
    const float* __restrict__ eps_l, const float* __restrict__ gns_l,
    const float* __restrict__ ofE, const float* __restrict__ ofG,
    const float* __restrict__ ofEs, const float* __restrict__ ofGs,
    const float* __restrict__ bias, float* __restrict__ out)
{
    int tid = threadIdx.x;
    int lane = tid & 63;
    int r = blockIdx.x * 4 + (tid >> 6);
    int b = r >> 12;
    float T1 = t1[r];
    float M2 = t2s[b * cN + cN - 1];
    float smax = T1 + M2;
    float m = fmaxf(smax, 0.2f * smax);
    float A  = __expf(smax - m);
    float Cc = __expf(0.2f * smax - m);
    int p = pidx[r];
    int c = p >> 4;
    size_t pr = ((size_t)b * cNP + p) * cK + lane;
    size_t cr = ((size_t)b * cNC1 + c) * cK + lane;
    float num = A * (EpL[pr] + ofE[cr]) + Cc * (GnL[pr] + ofG[cr]);
    float den = A * (eps_l[(size_t)b * cNP + p] + ofEs[b * cNC1 + c])
              + Cc * (gns_l[(size_t)b * cNP + p] + ofGs[b * cNC1 + c]);
    out[(size_t)r * cK + lane] = num / den + bias[lane];
}

// ---------------------------------------------------------------------------
extern "C" void kernel_launch(void* const* d_in, const int* in_sizes, int n_in,
                              void* d_out, int out_size, void* d_ws, size_t ws_size,
                              hipStream_t stream)
{
    const float* x    = (const float*)d_in[0];
    const float* Wa   = (const float*)d_in[1];
    const float* Wb   = (const float*)d_in[2];
    const float* wbb  = (const float*)d_in[3];
    const float* Wc   = (const float*)d_in[4];
    const float* wcb  = (const float*)d_in[5];
    const float* bias = (const float*)d_in[6];
    float* out = (float*)d_out;

    float* ws = (float*)d_ws;
    float* h     = ws + OFF_H;
    float* t1    = ws + OFF_T1;
    float* t2    = ws + OFF_T2;
    float* t2s   = ws + OFF_T2S;
    int*   idxs  = (int*)(ws + OFF_IDX);
    int*   pidx  = (int*)(ws + OFF_P);
    u64*   keysG = (u64*)(ws + OFF_KEYS);
    float* EpL   = ws + OFF_EPL;
    float* GnL   = ws + OFF_GNL;
    float* eps_l = ws + OFF_EPS;
    float* gns_l = ws + OFF_GNS;
    float* chE   = ws + OFF_CHE;
    float* chG   = ws + OFF_CHG;
    float* chEs  = ws + OFF_CHES;
    float* chGs  = ws + OFF_CHGS;
    float* ofE   = ws + OFF_OFE;
    float* ofG   = ws + OFF_OFG;
    float* ofEs  = ws + OFF_OFES;
    float* ofGs  = ws + OFF_OFGS;
    u16*   wab16 = (u16*)(ws + OFF_WB16);

    static int use_big_lds = -1;
    if (use_big_lds < 0) {
        hipError_t e = hipFuncSetAttribute((const void*)k_outf,
            hipFuncAttributeMaxDynamicSharedMemorySize, (int)SMEM_OUT);
        use_big_lds = (e == hipSuccess) ? 1 : 0;
    }

    k_prep<<<544, 256, 0, stream>>>(x, Wa, Wb, wbb, Wc, wcb, wab16, t1, t2, keysG);
    k_projrank<<<512, 256, 0, stream>>>(x, wab16, t1, t2, keysG, h, t2s, idxs, pidx);
    k_chunkscan<<<cB * cNC, 128, 0, stream>>>(t2s, idxs, h, EpL, GnL, eps_l, gns_l,
                                              chE, chG, chEs, chGs);
    if (use_big_lds) {
        k_outf<<<256, 256, SMEM_OUT, stream>>>(t1, t2s, pidx, EpL, GnL, eps_l, gns_l,
                                               chE, chG, chEs, chGs, bias, out);
    } else {
        k_offsets<<<cB * 2, 1024, 0, stream>>>(chE, chG, chEs, chGs, ofE, ofG, ofEs, ofGs);
        k_out<<<cNB / 4, 256, 0, stream>>>(t1, t2s, pidx, EpL, GnL, eps_l, gns_l,
                                           ofE, ofG, ofEs, ofGs, bias, out);
    }
}

// Round 8
// 149.775 us; speedup vs baseline: 1.0134x; 1.0134x over previous
//
#include <hip/hip_runtime.h>
#include <hip/hip_bf16.h>

// Problem constants
constexpr int cB = 4;
constexpr int cN = 4096;
constexpr int cD = 512;
constexpr int cK = 64;
constexpr int cNB = cB * cN;       // 16384 rows
constexpr int cNP = cN + 1;        // 4097 prefix rows
constexpr int cCS = 16;            // chunk size for scans
constexpr int cNC = cN / cCS;      // 256 chunks per batch
constexpr int cNC1 = cNC + 1;      // 257

typedef unsigned short u16;
typedef unsigned int u32;
typedef unsigned long long u64;
typedef __bf16 bf16x8 __attribute__((ext_vector_type(8)));
typedef float f32x4 __attribute__((ext_vector_type(4)));

// ---- workspace layout (in floats) ----
constexpr size_t OFF_H    = 0;                                  // cNB*cK
constexpr size_t OFF_T1   = OFF_H    + (size_t)cNB * cK;        // cNB
constexpr size_t OFF_T2   = OFF_T1   + cNB;                     // cNB
constexpr size_t OFF_T2S  = OFF_T2   + cNB;                     // cNB (sorted)
constexpr size_t OFF_IDX  = OFF_T2S  + cNB;                     // cNB (int)
constexpr size_t OFF_P    = OFF_IDX  + cNB;                     // cNB (int) split point per row
constexpr size_t OFF_EPL  = OFF_P    + cNB;                     // cB*cNP*cK
constexpr size_t OFF_GNL  = OFF_EPL  + (size_t)cB * cNP * cK;   // cB*cNP*cK
constexpr size_t OFF_EPS  = OFF_GNL  + (size_t)cB * cNP * cK;   // cB*cNP
constexpr size_t OFF_GNS  = OFF_EPS  + (size_t)cB * cNP;        // cB*cNP
constexpr size_t OFF_CHE  = OFF_GNS  + (size_t)cB * cNP;        // cB*cNC*cK
constexpr size_t OFF_CHG  = OFF_CHE  + (size_t)cB * cNC * cK;
constexpr size_t OFF_CHES = OFF_CHG  + (size_t)cB * cNC * cK;   // cB*cNC
constexpr size_t OFF_CHGS = OFF_CHES + (size_t)cB * cNC;
constexpr size_t OFF_OFE  = OFF_CHGS + (size_t)cB * cNC;        // cB*cNC1*cK (fallback only)
constexpr size_t OFF_OFG  = OFF_OFE  + (size_t)cB * cNC1 * cK;
constexpr size_t OFF_OFES = OFF_OFG  + (size_t)cB * cNC1 * cK;  // cB*cNC1
constexpr size_t OFF_OFGS = OFF_OFES + (size_t)cB * cNC1;

__device__ __forceinline__ u16 f2bf(float f) {
    unsigned u = __float_as_uint(f);
    u += 0x7fffu + ((u >> 16) & 1u);   // RNE
    return (u16)(u >> 16);
}
__device__ __forceinline__ u32 pk2(float a, float b) {
    return (u32)f2bf(a) | ((u32)f2bf(b) << 16);
}
// monotone float -> sortable uint (ascending)
__device__ __forceinline__ u32 f2sort(float f) {
    u32 b = __float_as_uint(f);
    u32 mask = (u32)((int)b >> 31);
    return b ^ (mask | 0x80000000u);
}

// ---------------------------------------------------------------------------
// k_prepg (768 blocks): blocks <512: one pass over x -> exact f32 t1/t2 via
// in-block fold of Wa with Wb/Wc. Blocks >=512: bf16-MFMA GEMM tile (64
// rows) with direct global->register fragments -- BOTH A (x) and B (Wa)
// read f32 and RNE-converted in-register (bit-identical to the old wab16
// path), so the GEMM has no dependency on the prep blocks and overlaps
// fully under prep's HBM pass. Zero LDS, zero barriers in the GEMM branch.
// ---------------------------------------------------------------------------
__global__ __launch_bounds__(256) void k_prepg(
    const float* __restrict__ x, const float* __restrict__ Wa,
    const float* __restrict__ Wb, const float* __restrict__ wbb,
    const float* __restrict__ Wc, const float* __restrict__ wcb,
    float* __restrict__ t1, float* __restrict__ t2, float* __restrict__ h)
{
    __shared__ float wabL[cD], wacL[cD];
    int t = threadIdx.x;
    if (blockIdx.x >= 512) {           // ---- GEMM branch ----
        int rowbase = ((int)blockIdx.x - 512) * 64;
        int w = t >> 6, lane = t & 63, m = lane & 15, quad = lane >> 4;
        const float* xg = x + (size_t)(rowbase + w * 16 + m) * cD + quad * 8;
        const float* wg = Wa + (size_t)m * cD + quad * 8;

        f32x4 acc[4] = {{0.f,0.f,0.f,0.f},{0.f,0.f,0.f,0.f},
                        {0.f,0.f,0.f,0.f},{0.f,0.f,0.f,0.f}};
#pragma unroll 4
        for (int s = 0; s < 16; ++s) {
            float4 xa  = *(const float4*)(xg + s * 32);
            float4 xb2 = *(const float4*)(xg + s * 32 + 4);
            uint4 xv = {pk2(xa.x, xa.y), pk2(xa.z, xa.w),
                        pk2(xb2.x, xb2.y), pk2(xb2.z, xb2.w)};
            bf16x8 av;
            __builtin_memcpy(&av, &xv, 16);
#pragma unroll
            for (int g = 0; g < 4; ++g) {
                float4 wa1 = *(const float4*)(wg + (size_t)g * 16 * cD + s * 32);
                float4 wa2 = *(const float4*)(wg + (size_t)g * 16 * cD + s * 32 + 4);
                uint4 wv = {pk2(wa1.x, wa1.y), pk2(wa1.z, wa1.w),
                            pk2(wa2.x, wa2.y), pk2(wa2.z, wa2.w)};
                bf16x8 bv;
                __builtin_memcpy(&bv, &wv, 16);
                acc[g] = __builtin_amdgcn_mfma_f32_16x16x32_bf16(av, bv, acc[g], 0, 0, 0);
            }
        }
#pragma unroll
        for (int g = 0; g < 4; ++g) {
#pragma unroll
            for (int r4 = 0; r4 < 4; ++r4) {
                int row = w * 16 + quad * 4 + r4;
                h[(size_t)(rowbase + row) * cK + g * 16 + m] = acc[g][r4];
            }
        }
        return;
    }
    // ---- prep branch (t1/t2) ----
    float s1a = 0.f, s2a = 0.f, s1b = 0.f, s2b = 0.f;
#pragma unroll 8
    for (int k = 0; k < cK; ++k) {
        float wbk = Wb[k], wck = Wc[k];
        float wa1 = Wa[k * cD + t];
        float wa2 = Wa[k * cD + t + 256];
        s1a += wa1 * wbk; s2a += wa1 * wck;
        s1b += wa2 * wbk; s2b += wa2 * wck;
    }
    wabL[t] = s1a; wacL[t] = s2a; wabL[t + 256] = s1b; wacL[t + 256] = s2b;
    __syncthreads();

    int w = t >> 6, lane = t & 63;
    int d1 = lane * 4, d2 = 256 + lane * 4;
    float4 wbA = *(const float4*)&wabL[d1], wbB = *(const float4*)&wabL[d2];
    float4 wcA = *(const float4*)&wacL[d1], wcB = *(const float4*)&wacL[d2];
    float wbbv = wbb[0], wcbv = wcb[0];
#pragma unroll 2
    for (int rr = 0; rr < 8; ++rr) {
        int row = blockIdx.x * 32 + w * 8 + rr;
        const float* xp = x + (size_t)row * cD;
        float4 a  = *(const float4*)(xp + d1);
        float4 bq = *(const float4*)(xp + d2);
        float p1 = a.x*wbA.x + a.y*wbA.y + a.z*wbA.z + a.w*wbA.w
                 + bq.x*wbB.x + bq.y*wbB.y + bq.z*wbB.z + bq.w*wbB.w;
        float p2 = a.x*wcA.x + a.y*wcA.y + a.z*wcA.z + a.w*wcA.w
                 + bq.x*wcB.x + bq.y*wcB.y + bq.z*wcB.z + bq.w*wcB.w;
#pragma unroll
        for (int off = 32; off > 0; off >>= 1) {
            p1 += __shfl_down(p1, off, 64);
            p2 += __shfl_down(p2, off, 64);
        }
        if (lane == 0) { t1[row] = p1 + wbbv; t2[row] = p2 + wcbv; }
    }
}

// ---------------------------------------------------------------------------
// k_rank (256 blocks): brute-force rank + split-point. Keys are 32-bit
// f2sort hi-words staged in 16 KB LDS; the u64 composite's low word was
// just the index j, and the scan loop KNOWS j -- so the tiebreak becomes
// (hi==myhi && j<myrow), and ds_read_b128 delivers 4 keys per 12-cycle
// broadcast issue (4x fewer LDS issues than the u64 version, bit-identical
// integer ranks). pidx fused as before (hi-only strict compare).
// ---------------------------------------------------------------------------
__global__ __launch_bounds__(256) void k_rank(
    const float* __restrict__ t1, const float* __restrict__ t2,
    float* __restrict__ t2s, int* __restrict__ idxs, int* __restrict__ pidx)
{
    __shared__ __align__(16) u32 his[cN];   // 16 KB
    __shared__ int part[512];               // 2 KB
    int t = threadIdx.x;
    int b = (int)blockIdx.x >> 6;
    int rowgrp = (int)blockIdx.x & 63;
    const float* t2b = t2 + (size_t)b * cN;
    for (int i = t; i < cN; i += 256)
        his[i] = f2sort(t2b[i]);
    __syncthreads();
    int lane = t & 63, subset = t >> 6;
    int myrow = rowgrp * 64 + lane;
    u32 myhi = his[myrow];
    u32 pk_hi = f2sort(-t1[(size_t)b * cN + myrow]);  // p-threshold hi word
    int s0 = subset * 1024;
    int cnt = 0, cnt2 = 0;
#pragma unroll 4
    for (int kk = 0; kk < 1024; kk += 4) {
        uint4 kv = *(const uint4*)&his[s0 + kk];
        int j0 = s0 + kk;
        cnt  += (kv.x < myhi || (kv.x == myhi && j0 + 0 < myrow)) ? 1 : 0;
        cnt  += (kv.y < myhi || (kv.y == myhi && j0 + 1 < myrow)) ? 1 : 0;
        cnt  += (kv.z < myhi || (kv.z == myhi && j0 + 2 < myrow)) ? 1 : 0;
        cnt  += (kv.w < myhi || (kv.w == myhi && j0 + 3 < myrow)) ? 1 : 0;
        cnt2 += (kv.x < pk_hi) ? 1 : 0;
        cnt2 += (kv.y < pk_hi) ? 1 : 0;
        cnt2 += (kv.z < pk_hi) ? 1 : 0;
        cnt2 += (kv.w < pk_hi) ? 1 : 0;
    }
    part[subset * 64 + lane] = cnt;
    part[256 + subset * 64 + lane] = cnt2;
    __syncthreads();
    if (t < 64) {
        int jj = rowgrp * 64 + t;
        int rank = part[t] + part[64 + t] + part[128 + t] + part[192 + t];
        int pc   = part[256 + t] + part[320 + t] + part[384 + t] + part[448 + t];
        t2s[(size_t)b * cN + rank] = t2b[jj];
        idxs[(size_t)b * cN + rank] = jj;
        pidx[(size_t)b * cN + jj] = pc;
    }
}

// ---------------------------------------------------------------------------
// k_chunkscan: 1024 blocks x 128 thr per (batch, chunk-of-16). The 16 h-rows
// are gathered ONCE into 4 KB LDS (wave w loads rows w*8..w*8+8); wave 0
// then does the E (suffix) scan, wave 1 the G (prefix) scan.
// ---------------------------------------------------------------------------
__global__ __launch_bounds__(128) void k_chunkscan(
    const float* __restrict__ t2s, const int* __restrict__ idxs,
    const float* __restrict__ h,
    float* __restrict__ EpL, float* __restrict__ GnL,
    float* __restrict__ eps_l, float* __restrict__ gns_l,
    float* __restrict__ chE, float* __restrict__ chG,
    float* __restrict__ chEs, float* __restrict__ chGs)
{
    __shared__ float hs[cCS][cK];      // 4 KB
    int t = threadIdx.x;
    int lane = t & 63, w = t >> 6;     // w in {0,1}
    int unit = blockIdx.x;
    int c = unit & (cNC - 1);
    int b = unit >> 8;
    int base = b * cN + c * cCS;
    size_t rowbase = ((size_t)b * cNP + c * cCS) * cK;
    int sbase = b * cNP + c * cCS;
    float M2 = t2s[b * cN + cN - 1];
    int   idxv = (lane < 8) ? idxs[base + w * 8 + lane] : 0;
    float t2v  = (lane < cCS) ? t2s[base + lane] : 0.f;

    // each wave gathers 8 h-rows into LDS
#pragma unroll
    for (int ii = 0; ii < 8; ++ii) {
        int j = __shfl(idxv, ii, 64);
        hs[w * 8 + ii][lane] = h[((size_t)b * cN + j) * cK + lane];
    }
    float slope = w ? 0.2f : 1.0f;
    float ev[cCS];
#pragma unroll
    for (int i = 0; i < cCS; ++i)
        ev[i] = __expf(slope * (__shfl(t2v, i, 64) - M2));
    __syncthreads();

    if (w == 0) {
        if (c == cNC - 1) {
            EpL[((size_t)b * cNP + cN) * cK + lane] = 0.f;
            if (lane == 0) eps_l[b * cNP + cN] = 0.f;
        }
        float acc = 0.f, accs = 0.f;
#pragma unroll
        for (int i = cCS - 1; i >= 0; --i) {
            acc += ev[i] * hs[i][lane]; accs += ev[i];
            EpL[rowbase + (size_t)i * cK + lane] = acc;
            if (lane == 0) eps_l[sbase + i] = accs;
        }
        chE[((size_t)b * cNC + c) * cK + lane] = acc;
        if (lane == 0) chEs[b * cNC + c] = accs;
    } else {
        if (c == cNC - 1) {
            GnL[((size_t)b * cNP + cN) * cK + lane] = 0.f;
            if (lane == 0) gns_l[b * cNP + cN] = 0.f;
        }
        float acc = 0.f, accs = 0.f;
#pragma unroll
        for (int i = 0; i < cCS; ++i) {
            GnL[rowbase + (size_t)i * cK + lane] = acc;
            if (lane == 0) gns_l[sbase + i] = accs;
            acc += ev[i] * hs[i][lane]; accs += ev[i];
        }
        chG[((size_t)b * cNC + c) * cK + lane] = acc;
        if (lane == 0) chGs[b * cNC + c] = accs;
    }
}

// ---------------------------------------------------------------------------
// k_outf: 256 blocks x 256 thr x 64 rows. Per-block prelude rebuilds the
// batch's offset tables in 135 KB dynamic LDS from chE/chG (replaces the
// k_offsets kernel + boundary). Main loop: 16 rows/wave, gather + combine.
// ---------------------------------------------------------------------------
constexpr unsigned SMEM_OUT = 134664;
__global__ __launch_bounds__(256, 1) void k_outf(
    const float* __restrict__ t1, const float* __restrict__ t2s,
    const int* __restrict__ pidx,
    const float* __restrict__ EpL, const float* __restrict__ GnL,
    const float* __restrict__ eps_l, const float* __restrict__ gns_l,
    const float* __restrict__ chE, const float* __restrict__ chG,
    const float* __restrict__ chEs, const float* __restrict__ chGs,
    const float* __restrict__ bias, float* __restrict__ out)
{
    extern __shared__ char sm[];
    float (*ofEl)[64] = (float(*)[64])(sm);                 // 257*64
    float (*ofGl)[64] = (float(*)[64])(sm + 65792);         // 257*64
    float* ofEsL      = (float*)(sm + 131584);              // 257
    float* ofGsL      = (float*)(sm + 132612);              // 257
    float (*wsum)[64] = (float(*)[64])(sm + 133640);        // 4*64

    int t = threadIdx.x, lane = t & 63, w = t >> 6;
    int blk = blockIdx.x;
    int b = blk >> 6;
    const float* chEb = chE + (size_t)b * cNC * cK;
    const float* chGb = chG + (size_t)b * cNC * cK;
    int c0 = w * 64;

    // ---- E suffix scan (vector) + scalar scans on waves 0/1 ----
    {
        float cv[64]; float s = 0.f;
#pragma unroll
        for (int i = 0; i < 64; ++i) { cv[i] = chEb[(size_t)(c0 + i) * cK + lane]; s += cv[i]; }
        wsum[w][lane] = s;
        if (w == 0) {
            float e0 = chEs[b*cNC + lane*4+0], e1 = chEs[b*cNC + lane*4+1];
            float e2 = chEs[b*cNC + lane*4+2], e3 = chEs[b*cNC + lane*4+3];
            float p = e0+e1+e2+e3, s2 = p;
#pragma unroll
            for (int off = 1; off < 64; off <<= 1) {
                float tv = __shfl_down(s2, off, 64);
                if (lane + off < 64) s2 += tv;
            }
            float excl = s2 - p;                  // sum over lanes > lane
            ofEsL[lane*4+0] = excl + e1 + e2 + e3;
            ofEsL[lane*4+1] = excl + e2 + e3;
            ofEsL[lane*4+2] = excl + e3;
            ofEsL[lane*4+3] = excl;
            if (lane == 0) ofEsL[cNC] = 0.f;
        } else if (w == 1) {
            float e0 = chGs[b*cNC + lane*4+0], e1 = chGs[b*cNC + lane*4+1];
            float e2 = chGs[b*cNC + lane*4+2], e3 = chGs[b*cNC + lane*4+3];
            float p = e0+e1+e2+e3, s2 = p;
#pragma unroll
            for (int off = 1; off < 64; off <<= 1) {
                float tv = __shfl_up(s2, off, 64);
                if (lane >= off) s2 += tv;
            }
            float excl = s2 - p;                  // sum over lanes < lane
            ofGsL[lane*4+0] = excl;
            ofGsL[lane*4+1] = excl + e0;
            ofGsL[lane*4+2] = excl + e0 + e1;
            ofGsL[lane*4+3] = excl + e0 + e1 + e2;
            if (lane == 63) ofGsL[cNC] = s2;
        }
        __syncthreads();
        float base = 0.f;
        for (int w2 = w + 1; w2 < 4; ++w2) base += wsum[w2][lane];
        float run = base;
#pragma unroll
        for (int i = 63; i >= 0; --i) { ofEl[c0 + i][lane] = run; run += cv[i]; }
        if (w == 0) ofEl[cNC][lane] = 0.f;
    }
    __syncthreads();    // wsum reuse guard (base reads done)
    // ---- G prefix scan (vector) ----
    {
        float cv[64]; float s = 0.f;
#pragma unroll
        for (int i = 0; i < 64; ++i) { cv[i] = chGb[(size_t)(c0 + i) * cK + lane]; s += cv[i]; }
        wsum[w][lane] = s;
        __syncthreads();
        float base = 0.f;
        for (int w2 = 0; w2 < w; ++w2) base += wsum[w2][lane];
        float run = base;
#pragma unroll
        for (int i = 0; i < 64; ++i) { ofGl[c0 + i][lane] = run; run += cv[i]; }
        if (w == 3) ofGl[cNC][lane] = run;
    }
    __syncthreads();

    // ---- main: 64 rows/block, 16 rows/wave ----
    float bv = bias[lane];
    float M2 = t2s[(size_t)b * cN + cN - 1];
    int r0 = blk * 64 + w * 16;
    const float* epsb = eps_l + (size_t)b * cNP;
    const float* gnsb = gns_l + (size_t)b * cNP;
#pragma unroll 8
    for (int i = 0; i < 16; ++i) {
        int r = r0 + i;
        float T1 = t1[r];
        float smax = T1 + M2;
        float m = fmaxf(smax, 0.2f * smax);      // leaky_relu(smax) = row max
        float A  = __expf(smax - m);
        float Cc = __expf(0.2f * smax - m);
        int p = pidx[r];
        int c = p >> 4;
        size_t pr = ((size_t)b * cNP + p) * cK + lane;
        float num = A * (EpL[pr] + ofEl[c][lane]) + Cc * (GnL[pr] + ofGl[c][lane]);
        float den = A * (epsb[p] + ofEsL[c]) + Cc * (gnsb[p] + ofGsL[c]);
        out[(size_t)r * cK + lane] = num / den + bv;
    }
}

// ---------------------------------------------------------------------------
// Fallback pair (only if the 135 KB LDS attribute is unavailable).
// ---------------------------------------------------------------------------
__global__ __launch_bounds__(1024) void k_offsets(
    const float* __restrict__ chE, const float* __restrict__ chG,
    const float* __restrict__ chEs, const float* __restrict__ chGs,
    float* __restrict__ ofE, float* __restrict__ ofG,
    float* __restrict__ ofEs, float* __restrict__ ofGs)
{
    __shared__ float wsum[16][64];
    int t = threadIdx.x;
    int lane = t & 63, w = t >> 6;
    int dir = blockIdx.x & 1;
    int b = blockIdx.x >> 1;
    const float* ch = dir ? chG : chE;
    float* of = dir ? ofG : ofE;
    int c0 = w * 16;

    float cv[16];
    float s = 0.f;
#pragma unroll
    for (int i = 0; i < 16; ++i) {
        cv[i] = ch[((size_t)b * cNC + c0 + i) * cK + lane];
        s += cv[i];
    }
    wsum[w][lane] = s;
    __syncthreads();
    float base = 0.f;
    if (dir == 0) { for (int w2 = w + 1; w2 < 16; ++w2) base += wsum[w2][lane]; }
    else          { for (int w2 = 0; w2 < w; ++w2) base += wsum[w2][lane]; }

    if (dir == 0) {
        float run = base;
#pragma unroll
        for (int i = 15; i >= 0; --i) {
            of[((size_t)b * cNC1 + c0 + i) * cK + lane] = run;
            run += cv[i];
        }
        if (w == 0) of[((size_t)b * cNC1 + cNC) * cK + lane] = 0.f;
    } else {
        float run = base;
#pragma unroll
        for (int i = 0; i < 16; ++i) {
            of[((size_t)b * cNC1 + c0 + i) * cK + lane] = run;
            run += cv[i];
        }
        if (w == 15) of[((size_t)b * cNC1 + cNC) * cK + lane] = run;
    }

    if (w == 0) {
        const float* chs = dir ? chGs : chEs;
        float* ofs = dir ? ofGs : ofEs;
        float e0 = chs[b * cNC + lane * 4 + 0];
        float e1 = chs[b * cNC + lane * 4 + 1];
        float e2 = chs[b * cNC + lane * 4 + 2];
        float e3 = chs[b * cNC + lane * 4 + 3];
        float p = e0 + e1 + e2 + e3;
        if (dir == 0) {
            float s2 = p;
#pragma unroll
            for (int off = 1; off < 64; off <<= 1) {
                float tv = __shfl_down(s2, off, 64);
                if (lane + off < 64) s2 += tv;
            }
            float excl = s2 - p;
            ofs[b * cNC1 + lane * 4 + 0] = excl + e1 + e2 + e3;
            ofs[b * cNC1 + lane * 4 + 1] = excl + e2 + e3;
            ofs[b * cNC1 + lane * 4 + 2] = excl + e3;
            ofs[b * cNC1 + lane * 4 + 3] = excl;
            if (lane == 0) ofs[b * cNC1 + cNC] = 0.f;
        } else {
            float s2 = p;
#pragma unroll
            for (int off = 1; off < 64; off <<= 1) {
                float tv = __shfl_up(s2, off, 64);
                if (lane >= off) s2 += tv;
            }
            float excl = s2 - p;
            ofs[b * cNC1 + lane * 4 + 0] = excl;
            ofs[b * cNC1 + lane * 4 + 1] = excl + e0;
            ofs[b * cNC1 + lane * 4 + 2] = excl + e0 + e1;
            ofs[b * cNC1 + lane * 4 + 3] = excl + e0 + e1 + e2;
            if (lane == 63) ofs[b * cNC1 + cNC] = s2;
        }
    }
}

__global__ __launch_bounds__(256) void k_out(
    const float* __restrict__ t1, const float* __restrict__ t2s,
    const int* __restrict__ pidx,
    const float* __restrict__ EpL, const float* __restrict__ GnL,
    const float* __restrict__ eps_l, const float* __restrict__ gns_l,
    const float* __restrict__ ofE, const float* __restrict__ ofG,
    const float* __restrict__ ofEs, const float* __restrict__ ofGs,
    const float* __restrict__ bias, float* __restrict__ out)
{
    int tid = threadIdx.x;
    int lane = tid & 63;
    int r = blockIdx.x * 4 + (tid >> 6);
    int b = r >> 12;
    float T1 = t1[r];
    float M2 = t2s[b * cN + cN - 1];
    float smax = T1 + M2;
    float m = fmaxf(smax, 0.2f * smax);
    float A  = __expf(smax - m);
    float Cc = __expf(0.2f * smax - m);
    int p = pidx[r];
    int c = p >> 4;
    size_t pr = ((size_t)b * cNP + p) * cK + lane;
    size_t cr = ((size_t)b * cNC1 + c) * cK + lane;
    float num = A * (EpL[pr] + ofE[cr]) + Cc * (GnL[pr] + ofG[cr]);
    float den = A * (eps_l[(size_t)b * cNP + p] + ofEs[b * cNC1 + c])
              + Cc * (gns_l[(size_t)b * cNP + p] + ofGs[b * cNC1 + c]);
    out[(size_t)r * cK + lane] = num / den + bias[lane];
}

// ---------------------------------------------------------------------------
extern "C" void kernel_launch(void* const* d_in, const int* in_sizes, int n_in,
                              void* d_out, int out_size, void* d_ws, size_t ws_size,
                              hipStream_t stream)
{
    const float* x    = (const float*)d_in[0];
    const float* Wa   = (const float*)d_in[1];
    const float* Wb   = (const float*)d_in[2];
    const float* wbb  = (const float*)d_in[3];
    const float* Wc   = (const float*)d_in[4];
    const float* wcb  = (const float*)d_in[5];
    const float* bias = (const float*)d_in[6];
    float* out = (float*)d_out;

    float* ws = (float*)d_ws;
    float* h     = ws + OFF_H;
    float* t1    = ws + OFF_T1;
    float* t2    = ws + OFF_T2;
    float* t2s   = ws + OFF_T2S;
    int*   idxs  = (int*)(ws + OFF_IDX);
    int*   pidx  = (int*)(ws + OFF_P);
    float* EpL   = ws + OFF_EPL;
    float* GnL   = ws + OFF_GNL;
    float* eps_l = ws + OFF_EPS;
    float* gns_l = ws + OFF_GNS;
    float* chE   = ws + OFF_CHE;
    float* chG   = ws + OFF_CHG;
    float* chEs  = ws + OFF_CHES;
    float* chGs  = ws + OFF_CHGS;
    float* ofE   = ws + OFF_OFE;
    float* ofG   = ws + OFF_OFG;
    float* ofEs  = ws + OFF_OFES;
    float* ofGs  = ws + OFF_OFGS;

    static int use_big_lds = -1;
    if (use_big_lds < 0) {
        hipError_t e = hipFuncSetAttribute((const void*)k_outf,
            hipFuncAttributeMaxDynamicSharedMemorySize, (int)SMEM_OUT);
        use_big_lds = (e == hipSuccess) ? 1 : 0;
    }

    k_prepg<<<768, 256, 0, stream>>>(x, Wa, Wb, wbb, Wc, wcb, t1, t2, h);
    k_rank<<<256, 256, 0, stream>>>(t1, t2, t2s, idxs, pidx);
    k_chunkscan<<<cB * cNC, 128, 0, stream>>>(t2s, idxs, h, EpL, GnL, eps_l, gns_l,
                                              chE, chG, chEs, chGs);
    if (use_big_lds) {
        k_outf<<<256, 256, SMEM_OUT, stream>>>(t1, t2s, pidx, EpL, GnL, eps_l, gns_l,
                                               chE, chG, chEs, chGs, bias, out);
    } else {
        k_offsets<<<cB * 2, 1024, 0, stream>>>(chE, chG, chEs, chGs, ofE, ofG, ofEs, ofGs);
        k_out<<<cNB / 4, 256, 0, stream>>>(t1, t2s, pidx, EpL, GnL, eps_l, gns_l,
                                           ofE, ofG, ofEs, ofGs, bias, out);
    }
}

// Round 9
// 139.381 us; speedup vs baseline: 1.0890x; 1.0746x over previous
//
#include <hip/hip_runtime.h>
#include <hip/hip_bf16.h>

// Problem constants
constexpr int cB = 4;
constexpr int cN = 4096;
constexpr int cD = 512;
constexpr int cK = 64;
constexpr int cNB = cB * cN;       // 16384 rows
constexpr int cNP = cN + 1;        // 4097 prefix rows
constexpr int cCS = 16;            // chunk size for scans
constexpr int cNC = cN / cCS;      // 256 chunks per batch
constexpr int cNC1 = cNC + 1;      // 257

typedef unsigned short u16;
typedef unsigned int u32;
typedef unsigned long long u64;
typedef __bf16 bf16x8 __attribute__((ext_vector_type(8)));
typedef float f32x4 __attribute__((ext_vector_type(4)));

// ---- workspace layout (in floats) ----
constexpr size_t OFF_H    = 0;                                  // cNB*cK
constexpr size_t OFF_T1   = OFF_H    + (size_t)cNB * cK;        // cNB
constexpr size_t OFF_T2   = OFF_T1   + cNB;                     // cNB
constexpr size_t OFF_T2S  = OFF_T2   + cNB;                     // cNB (sorted)
constexpr size_t OFF_IDX  = OFF_T2S  + cNB;                     // cNB (int)
constexpr size_t OFF_P    = OFF_IDX  + cNB;                     // cNB (int) split point per row
constexpr size_t OFF_EPL  = OFF_P    + cNB;                     // cB*cNP*cK
constexpr size_t OFF_GNL  = OFF_EPL  + (size_t)cB * cNP * cK;   // cB*cNP*cK
constexpr size_t OFF_EPS  = OFF_GNL  + (size_t)cB * cNP * cK;   // cB*cNP
constexpr size_t OFF_GNS  = OFF_EPS  + (size_t)cB * cNP;        // cB*cNP
constexpr size_t OFF_CHE  = OFF_GNS  + (size_t)cB * cNP;        // cB*cNC*cK
constexpr size_t OFF_CHG  = OFF_CHE  + (size_t)cB * cNC * cK;
constexpr size_t OFF_CHES = OFF_CHG  + (size_t)cB * cNC * cK;   // cB*cNC
constexpr size_t OFF_CHGS = OFF_CHES + (size_t)cB * cNC;
constexpr size_t OFF_OFE  = OFF_CHGS + (size_t)cB * cNC;        // cB*cNC1*cK (fallback only)
constexpr size_t OFF_OFG  = OFF_OFE  + (size_t)cB * cNC1 * cK;
constexpr size_t OFF_OFES = OFF_OFG  + (size_t)cB * cNC1 * cK;  // cB*cNC1
constexpr size_t OFF_OFGS = OFF_OFES + (size_t)cB * cNC1;
constexpr size_t OFF_WB16 = OFF_OFGS + (size_t)cB * cNC1;       // cK*cD u16

__device__ __forceinline__ u16 f2bf(float f) {
    unsigned u = __float_as_uint(f);
    u += 0x7fffu + ((u >> 16) & 1u);   // RNE
    return (u16)(u >> 16);
}
__device__ __forceinline__ u32 pk2(float a, float b) {
    return (u32)f2bf(a) | ((u32)f2bf(b) << 16);
}
// monotone float -> sortable uint (ascending)
__device__ __forceinline__ u32 f2sort(float f) {
    u32 b = __float_as_uint(f);
    u32 mask = (u32)((int)b >> 31);
    return b ^ (mask | 0x80000000u);
}

// ---------------------------------------------------------------------------
// k_prep (544 blocks): blocks <512: one pass over x -> exact f32 t1/t2 via
// in-block fold of Wa with Wb/Wc. Blocks >=512: Wa -> wab16 (bf16 B operand).
// ---------------------------------------------------------------------------
__global__ __launch_bounds__(256) void k_prep(
    const float* __restrict__ x, const float* __restrict__ Wa,
    const float* __restrict__ Wb, const float* __restrict__ wbb,
    const float* __restrict__ Wc, const float* __restrict__ wcb,
    u16* __restrict__ wab16, float* __restrict__ t1, float* __restrict__ t2)
{
    __shared__ float wabL[cD], wacL[cD];
    int t = threadIdx.x;
    if (blockIdx.x >= 512) {           // wprep slice: 32 blocks x 256 x 4 elems
        int i4 = (((int)blockIdx.x - 512) * 256 + t) * 4;
        float4 v = *(const float4*)(Wa + i4);
        uint2 p = {pk2(v.x, v.y), pk2(v.z, v.w)};
        *(uint2*)(wab16 + i4) = p;
        return;
    }
    float s1a = 0.f, s2a = 0.f, s1b = 0.f, s2b = 0.f;
#pragma unroll 8
    for (int k = 0; k < cK; ++k) {
        float wbk = Wb[k], wck = Wc[k];
        float wa1 = Wa[k * cD + t];
        float wa2 = Wa[k * cD + t + 256];
        s1a += wa1 * wbk; s2a += wa1 * wck;
        s1b += wa2 * wbk; s2b += wa2 * wck;
    }
    wabL[t] = s1a; wacL[t] = s2a; wabL[t + 256] = s1b; wacL[t + 256] = s2b;
    __syncthreads();

    int w = t >> 6, lane = t & 63;
    int d1 = lane * 4, d2 = 256 + lane * 4;
    float4 wbA = *(const float4*)&wabL[d1], wbB = *(const float4*)&wabL[d2];
    float4 wcA = *(const float4*)&wacL[d1], wcB = *(const float4*)&wacL[d2];
    float wbbv = wbb[0], wcbv = wcb[0];
#pragma unroll 2
    for (int rr = 0; rr < 8; ++rr) {
        int row = blockIdx.x * 32 + w * 8 + rr;
        const float* xp = x + (size_t)row * cD;
        float4 a  = *(const float4*)(xp + d1);
        float4 bq = *(const float4*)(xp + d2);
        float p1 = a.x*wbA.x + a.y*wbA.y + a.z*wbA.z + a.w*wbA.w
                 + bq.x*wbB.x + bq.y*wbB.y + bq.z*wbB.z + bq.w*wbB.w;
        float p2 = a.x*wcA.x + a.y*wcA.y + a.z*wcA.z + a.w*wcA.w
                 + bq.x*wcB.x + bq.y*wcB.y + bq.z*wcB.z + bq.w*wcB.w;
#pragma unroll
        for (int off = 32; off > 0; off >>= 1) {
            p1 += __shfl_down(p1, off, 64);
            p2 += __shfl_down(p2, off, 64);
        }
        if (lane == 0) { t1[row] = p1 + wbbv; t2[row] = p2 + wcbv; }
    }
}

// ---------------------------------------------------------------------------
// k_projrank (512 blocks): blocks <256 do the bf16-MFMA GEMM tile (64 rows)
// with direct global->register fragments (zero LDS, zero barriers, A from x
// f32 RNE-converted in-register, B from L1-hot wab16). Blocks >=256 do the
// brute-force rank + split-point with u32 keys: the u64 composite's low
// word was just the index j, and the scan loop KNOWS j -- tiebreak is
// (hi==myhi && j<myrow), so ds_read_b128 delivers 4 keys per broadcast
// issue (4x fewer LDS issues, bit-identical ranks). LDS 18 KB (was 34.75)
// -> more co-resident blocks, better GEMM/rank pipe interleave per CU.
// ---------------------------------------------------------------------------
__global__ __launch_bounds__(256) void k_projrank(
    const float* __restrict__ x, const u16* __restrict__ wab16,
    const float* __restrict__ t1, const float* __restrict__ t2,
    float* __restrict__ h, float* __restrict__ t2s, int* __restrict__ idxs,
    int* __restrict__ pidx)
{
    __shared__ __align__(16) u32 his[cN];   // 16 KB (rank keys)
    __shared__ int part[512];               // 2 KB  (rank partials)
    int t = threadIdx.x;
    if (blockIdx.x < 256) {
        int rowbase = blockIdx.x * 64;
        int w = t >> 6, lane = t & 63, m = lane & 15, quad = lane >> 4;
        const float* xg = x + (size_t)(rowbase + w * 16 + m) * cD + quad * 8;
        const u16* wg = wab16 + (size_t)m * cD + quad * 8;

        f32x4 acc[4] = {{0.f,0.f,0.f,0.f},{0.f,0.f,0.f,0.f},
                        {0.f,0.f,0.f,0.f},{0.f,0.f,0.f,0.f}};
#pragma unroll 4
        for (int s = 0; s < 16; ++s) {
            float4 xa  = *(const float4*)(xg + s * 32);
            float4 xb2 = *(const float4*)(xg + s * 32 + 4);
            uint4 xv = {pk2(xa.x, xa.y), pk2(xa.z, xa.w),
                        pk2(xb2.x, xb2.y), pk2(xb2.z, xb2.w)};
            bf16x8 av;
            __builtin_memcpy(&av, &xv, 16);
#pragma unroll
            for (int g = 0; g < 4; ++g) {
                uint4 wv = *(const uint4*)(wg + (size_t)g * 16 * cD + s * 32);
                bf16x8 bv;
                __builtin_memcpy(&bv, &wv, 16);
                acc[g] = __builtin_amdgcn_mfma_f32_16x16x32_bf16(av, bv, acc[g], 0, 0, 0);
            }
        }
#pragma unroll
        for (int g = 0; g < 4; ++g) {
#pragma unroll
            for (int r4 = 0; r4 < 4; ++r4) {
                int row = w * 16 + quad * 4 + r4;
                h[(size_t)(rowbase + row) * cK + g * 16 + m] = acc[g][r4];
            }
        }
    } else {
        int rb = blockIdx.x - 256;
        int b = rb >> 6;
        int rowgrp = rb & 63;
        const float* t2b = t2 + (size_t)b * cN;
        for (int i = t; i < cN; i += 256)
            his[i] = f2sort(t2b[i]);
        __syncthreads();
        int lane = t & 63, subset = t >> 6;
        int myrow = rowgrp * 64 + lane;
        u32 myhi = his[myrow];
        u32 pk_hi = f2sort(-t1[(size_t)b * cN + myrow]);  // p-threshold hi word
        int s0 = subset * 1024;
        int cnt = 0, cnt2 = 0;
#pragma unroll 4
        for (int kk = 0; kk < 1024; kk += 4) {
            uint4 kv = *(const uint4*)&his[s0 + kk];
            int j0 = s0 + kk;
            cnt  += (kv.x < myhi || (kv.x == myhi && j0 + 0 < myrow)) ? 1 : 0;
            cnt  += (kv.y < myhi || (kv.y == myhi && j0 + 1 < myrow)) ? 1 : 0;
            cnt  += (kv.z < myhi || (kv.z == myhi && j0 + 2 < myrow)) ? 1 : 0;
            cnt  += (kv.w < myhi || (kv.w == myhi && j0 + 3 < myrow)) ? 1 : 0;
            cnt2 += (kv.x < pk_hi) ? 1 : 0;
            cnt2 += (kv.y < pk_hi) ? 1 : 0;
            cnt2 += (kv.z < pk_hi) ? 1 : 0;
            cnt2 += (kv.w < pk_hi) ? 1 : 0;
        }
        part[subset * 64 + lane] = cnt;
        part[256 + subset * 64 + lane] = cnt2;
        __syncthreads();
        if (t < 64) {
            int jj = rowgrp * 64 + t;
            int rank = part[t] + part[64 + t] + part[128 + t] + part[192 + t];
            int pc   = part[256 + t] + part[320 + t] + part[384 + t] + part[448 + t];
            t2s[(size_t)b * cN + rank] = t2b[jj];
            idxs[(size_t)b * cN + rank] = jj;
            pidx[(size_t)b * cN + jj] = pc;
        }
    }
}

// ---------------------------------------------------------------------------
// k_chunkscan: 1024 blocks x 128 thr per (batch, chunk-of-16). The 16 h-rows
// are gathered ONCE into 4 KB LDS (wave w loads rows w*8..w*8+8); wave 0
// then does the E (suffix) scan, wave 1 the G (prefix) scan.
// ---------------------------------------------------------------------------
__global__ __launch_bounds__(128) void k_chunkscan(
    const float* __restrict__ t2s, const int* __restrict__ idxs,
    const float* __restrict__ h,
    float* __restrict__ EpL, float* __restrict__ GnL,
    float* __restrict__ eps_l, float* __restrict__ gns_l,
    float* __restrict__ chE, float* __restrict__ chG,
    float* __restrict__ chEs, float* __restrict__ chGs)
{
    __shared__ float hs[cCS][cK];      // 4 KB
    int t = threadIdx.x;
    int lane = t & 63, w = t >> 6;     // w in {0,1}
    int unit = blockIdx.x;
    int c = unit & (cNC - 1);
    int b = unit >> 8;
    int base = b * cN + c * cCS;
    size_t rowbase = ((size_t)b * cNP + c * cCS) * cK;
    int sbase = b * cNP + c * cCS;
    float M2 = t2s[b * cN + cN - 1];
    int   idxv = (lane < 8) ? idxs[base + w * 8 + lane] : 0;
    float t2v  = (lane < cCS) ? t2s[base + lane] : 0.f;

    // each wave gathers 8 h-rows into LDS
#pragma unroll
    for (int ii = 0; ii < 8; ++ii) {
        int j = __shfl(idxv, ii, 64);
        hs[w * 8 + ii][lane] = h[((size_t)b * cN + j) * cK + lane];
    }
    float slope = w ? 0.2f : 1.0f;
    float ev[cCS];
#pragma unroll
    for (int i = 0; i < cCS; ++i)
        ev[i] = __expf(slope * (__shfl(t2v, i, 64) - M2));
    __syncthreads();

    if (w == 0) {
        if (c == cNC - 1) {
            EpL[((size_t)b * cNP + cN) * cK + lane] = 0.f;
            if (lane == 0) eps_l[b * cNP + cN] = 0.f;
        }
        float acc = 0.f, accs = 0.f;
#pragma unroll
        for (int i = cCS - 1; i >= 0; --i) {
            acc += ev[i] * hs[i][lane]; accs += ev[i];
            EpL[rowbase + (size_t)i * cK + lane] = acc;
            if (lane == 0) eps_l[sbase + i] = accs;
        }
        chE[((size_t)b * cNC + c) * cK + lane] = acc;
        if (lane == 0) chEs[b * cNC + c] = accs;
    } else {
        if (c == cNC - 1) {
            GnL[((size_t)b * cNP + cN) * cK + lane] = 0.f;
            if (lane == 0) gns_l[b * cNP + cN] = 0.f;
        }
        float acc = 0.f, accs = 0.f;
#pragma unroll
        for (int i = 0; i < cCS; ++i) {
            GnL[rowbase + (size_t)i * cK + lane] = acc;
            if (lane == 0) gns_l[sbase + i] = accs;
            acc += ev[i] * hs[i][lane]; accs += ev[i];
        }
        chG[((size_t)b * cNC + c) * cK + lane] = acc;
        if (lane == 0) chGs[b * cNC + c] = accs;
    }
}

// ---------------------------------------------------------------------------
// k_outf: 256 blocks x 256 thr x 64 rows. Per-block prelude rebuilds the
// batch's offset tables in 135 KB dynamic LDS from chE/chG (replaces the
// k_offsets kernel + boundary). Main loop: 16 rows/wave, gather + combine.
// ---------------------------------------------------------------------------
constexpr unsigned SMEM_OUT = 134664;
__global__ __launch_bounds__(256, 1) void k_outf(
    const float* __restrict__ t1, const float* __restrict__ t2s,
    const int* __restrict__ pidx,
    const float* __restrict__ EpL, const float* __restrict__ GnL,
    const float* __restrict__ eps_l, const float* __restrict__ gns_l,
    const float* __restrict__ chE, const float* __restrict__ chG,
    const float* __restrict__ chEs, const float* __restrict__ chGs,
    const float* __restrict__ bias, float* __restrict__ out)
{
    extern __shared__ char sm[];
    float (*ofEl)[64] = (float(*)[64])(sm);                 // 257*64
    float (*ofGl)[64] = (float(*)[64])(sm + 65792);         // 257*64
    float* ofEsL      = (float*)(sm + 131584);              // 257
    float* ofGsL      = (float*)(sm + 132612);              // 257
    float (*wsum)[64] = (float(*)[64])(sm + 133640);        // 4*64

    int t = threadIdx.x, lane = t & 63, w = t >> 6;
    int blk = blockIdx.x;
    int b = blk >> 6;
    const float* chEb = chE + (size_t)b * cNC * cK;
    const float* chGb = chG + (size_t)b * cNC * cK;
    int c0 = w * 64;

    // ---- E suffix scan (vector) + scalar scans on waves 0/1 ----
    {
        float cv[64]; float s = 0.f;
#pragma unroll
        for (int i = 0; i < 64; ++i) { cv[i] = chEb[(size_t)(c0 + i) * cK + lane]; s += cv[i]; }
        wsum[w][lane] = s;
        if (w == 0) {
            float e0 = chEs[b*cNC + lane*4+0], e1 = chEs[b*cNC + lane*4+1];
            float e2 = chEs[b*cNC + lane*4+2], e3 = chEs[b*cNC + lane*4+3];
            float p = e0+e1+e2+e3, s2 = p;
#pragma unroll
            for (int off = 1; off < 64; off <<= 1) {
                float tv = __shfl_down(s2, off, 64);
                if (lane + off < 64) s2 += tv;
            }
            float excl = s2 - p;                  // sum over lanes > lane
            ofEsL[lane*4+0] = excl + e1 + e2 + e3;
            ofEsL[lane*4+1] = excl + e2 + e3;
            ofEsL[lane*4+2] = excl + e3;
            ofEsL[lane*4+3] = excl;
            if (lane == 0) ofEsL[cNC] = 0.f;
        } else if (w == 1) {
            float e0 = chGs[b*cNC + lane*4+0], e1 = chGs[b*cNC + lane*4+1];
            float e2 = chGs[b*cNC + lane*4+2], e3 = chGs[b*cNC + lane*4+3];
            float p = e0+e1+e2+e3, s2 = p;
#pragma unroll
            for (int off = 1; off < 64; off <<= 1) {
                float tv = __shfl_up(s2, off, 64);
                if (lane >= off) s2 += tv;
            }
            float excl = s2 - p;                  // sum over lanes < lane
            ofGsL[lane*4+0] = excl;
            ofGsL[lane*4+1] = excl + e0;
            ofGsL[lane*4+2] = excl + e0 + e1;
            ofGsL[lane*4+3] = excl + e0 + e1 + e2;
            if (lane == 63) ofGsL[cNC] = s2;
        }
        __syncthreads();
        float base = 0.f;
        for (int w2 = w + 1; w2 < 4; ++w2) base += wsum[w2][lane];
        float run = base;
#pragma unroll
        for (int i = 63; i >= 0; --i) { ofEl[c0 + i][lane] = run; run += cv[i]; }
        if (w == 0) ofEl[cNC][lane] = 0.f;
    }
    __syncthreads();    // wsum reuse guard (base reads done)
    // ---- G prefix scan (vector) ----
    {
        float cv[64]; float s = 0.f;
#pragma unroll
        for (int i = 0; i < 64; ++i) { cv[i] = chGb[(size_t)(c0 + i) * cK + lane]; s += cv[i]; }
        wsum[w][lane] = s;
        __syncthreads();
        float base = 0.f;
        for (int w2 = 0; w2 < w; ++w2) base += wsum[w2][lane];
        float run = base;
#pragma unroll
        for (int i = 0; i < 64; ++i) { ofGl[c0 + i][lane] = run; run += cv[i]; }
        if (w == 3) ofGl[cNC][lane] = run;
    }
    __syncthreads();

    // ---- main: 64 rows/block, 16 rows/wave ----
    float bv = bias[lane];
    float M2 = t2s[(size_t)b * cN + cN - 1];
    int r0 = blk * 64 + w * 16;
    const float* epsb = eps_l + (size_t)b * cNP;
    const float* gnsb = gns_l + (size_t)b * cNP;
#pragma unroll 8
    for (int i = 0; i < 16; ++i) {
        int r = r0 + i;
        float T1 = t1[r];
        float smax = T1 + M2;
        float m = fmaxf(smax, 0.2f * smax);      // leaky_relu(smax) = row max
        float A  = __expf(smax - m);
        float Cc = __expf(0.2f * smax - m);
        int p = pidx[r];
        int c = p >> 4;
        size_t pr = ((size_t)b * cNP + p) * cK + lane;
        float num = A * (EpL[pr] + ofEl[c][lane]) + Cc * (GnL[pr] + ofGl[c][lane]);
        float den = A * (epsb[p] + ofEsL[c]) + Cc * (gnsb[p] + ofGsL[c]);
        out[(size_t)r * cK + lane] = num / den + bv;
    }
}

// ---------------------------------------------------------------------------
// Fallback pair (only if the 135 KB LDS attribute is unavailable).
// ---------------------------------------------------------------------------
__global__ __launch_bounds__(1024) void k_offsets(
    const float* __restrict__ chE, const float* __restrict__ chG,
    const float* __restrict__ chEs, const float* __restrict__ chGs,
    float* __restrict__ ofE, float* __restrict__ ofG,
    float* __restrict__ ofEs, float* __restrict__ ofGs)
{
    __shared__ float wsum[16][64];
    int t = threadIdx.x;
    int lane = t & 63, w = t >> 6;
    int dir = blockIdx.x & 1;
    int b = blockIdx.x >> 1;
    const float* ch = dir ? chG : chE;
    float* of = dir ? ofG : ofE;
    int c0 = w * 16;

    float cv[16];
    float s = 0.f;
#pragma unroll
    for (int i = 0; i < 16; ++i) {
        cv[i] = ch[((size_t)b * cNC + c0 + i) * cK + lane];
        s += cv[i];
    }
    wsum[w][lane] = s;
    __syncthreads();
    float base = 0.f;
    if (dir == 0) { for (int w2 = w + 1; w2 < 16; ++w2) base += wsum[w2][lane]; }
    else          { for (int w2 = 0; w2 < w; ++w2) base += wsum[w2][lane]; }

    if (dir == 0) {
        float run = base;
#pragma unroll
        for (int i = 15; i >= 0; --i) {
            of[((size_t)b * cNC1 + c0 + i) * cK + lane] = run;
            run += cv[i];
        }
        if (w == 0) of[((size_t)b * cNC1 + cNC) * cK + lane] = 0.f;
    } else {
        float run = base;
#pragma unroll
        for (int i = 0; i < 16; ++i) {
            of[((size_t)b * cNC1 + c0 + i) * cK + lane] = run;
            run += cv[i];
        }
        if (w == 15) of[((size_t)b * cNC1 + cNC) * cK + lane] = run;
    }

    if (w == 0) {
        const float* chs = dir ? chGs : chEs;
        float* ofs = dir ? ofGs : ofEs;
        float e0 = chs[b * cNC + lane * 4 + 0];
        float e1 = chs[b * cNC + lane * 4 + 1];
        float e2 = chs[b * cNC + lane * 4 + 2];
        float e3 = chs[b * cNC + lane * 4 + 3];
        float p = e0 + e1 + e2 + e3;
        if (dir == 0) {
            float s2 = p;
#pragma unroll
            for (int off = 1; off < 64; off <<= 1) {
                float tv = __shfl_down(s2, off, 64);
                if (lane + off < 64) s2 += tv;
            }
            float excl = s2 - p;
            ofs[b * cNC1 + lane * 4 + 0] = excl + e1 + e2 + e3;
            ofs[b * cNC1 + lane * 4 + 1] = excl + e2 + e3;
            ofs[b * cNC1 + lane * 4 + 2] = excl + e3;
            ofs[b * cNC1 + lane * 4 + 3] = excl;
            if (lane == 0) ofs[b * cNC1 + cNC] = 0.f;
        } else {
            float s2 = p;
#pragma unroll
            for (int off = 1; off < 64; off <<= 1) {
                float tv = __shfl_up(s2, off, 64);
                if (lane >= off) s2 += tv;
            }
            float excl = s2 - p;
            ofs[b * cNC1 + lane * 4 + 0] = excl;
            ofs[b * cNC1 + lane * 4 + 1] = excl + e0;
            ofs[b * cNC1 + lane * 4 + 2] = excl + e0 + e1;
            ofs[b * cNC1 + lane * 4 + 3] = excl + e0 + e1 + e2;
            if (lane == 63) ofs[b * cNC1 + cNC] = s2;
        }
    }
}

__global__ __launch_bounds__(256) void k_out(
    const float* __restrict__ t1, const float* __restrict__ t2s,
    const int* __restrict__ pidx,
    const float* __restrict__ EpL, const float* __restrict__ GnL,
    const float* __restrict__ eps_l, const float* __restrict__ gns_l,
    const float* __restrict__ ofE, const float* __restrict__ ofG,
    const float* __restrict__ ofEs, const float* __restrict__ ofGs,
    const float* __restrict__ bias, float* __restrict__ out)
{
    int tid = threadIdx.x;
    int lane = tid & 63;
    int r = blockIdx.x * 4 + (tid >> 6);
    int b = r >> 12;
    float T1 = t1[r];
    float M2 = t2s[b * cN + cN - 1];
    float smax = T1 + M2;
    float m = fmaxf(smax, 0.2f * smax);
    float A  = __expf(smax - m);
    float Cc = __expf(0.2f * smax - m);
    int p = pidx[r];
    int c = p >> 4;
    size_t pr = ((size_t)b * cNP + p) * cK + lane;
    size_t cr = ((size_t)b * cNC1 + c) * cK + lane;
    float num = A * (EpL[pr] + ofE[cr]) + Cc * (GnL[pr] + ofG[cr]);
    float den = A * (eps_l[(size_t)b * cNP + p] + ofEs[b * cNC1 + c])
              + Cc * (gns_l[(size_t)b * cNP + p] + ofGs[b * cNC1 + c]);
    out[(size_t)r * cK + lane] = num / den + bias[lane];
}

// ---------------------------------------------------------------------------
extern "C" void kernel_launch(void* const* d_in, const int* in_sizes, int n_in,
                              void* d_out, int out_size, void* d_ws, size_t ws_size,
                              hipStream_t stream)
{
    const float* x    = (const float*)d_in[0];
    const float* Wa   = (const float*)d_in[1];
    const float* Wb   = (const float*)d_in[2];
    const float* wbb  = (const float*)d_in[3];
    const float* Wc   = (const float*)d_in[4];
    const float* wcb  = (const float*)d_in[5];
    const float* bias = (const float*)d_in[6];
    float* out = (float*)d_out;

    float* ws = (float*)d_ws;
    float* h     = ws + OFF_H;
    float* t1    = ws + OFF_T1;
    float* t2    = ws + OFF_T2;
    float* t2s   = ws + OFF_T2S;
    int*   idxs  = (int*)(ws + OFF_IDX);
    int*   pidx  = (int*)(ws + OFF_P);
    float* EpL   = ws + OFF_EPL;
    float* GnL   = ws + OFF_GNL;
    float* eps_l = ws + OFF_EPS;
    float* gns_l = ws + OFF_GNS;
    float* chE   = ws + OFF_CHE;
    float* chG   = ws + OFF_CHG;
    float* chEs  = ws + OFF_CHES;
    float* chGs  = ws + OFF_CHGS;
    float* ofE   = ws + OFF_OFE;
    float* ofG   = ws + OFF_OFG;
    float* ofEs  = ws + OFF_OFES;
    float* ofGs  = ws + OFF_OFGS;
    u16*   wab16 = (u16*)(ws + OFF_WB16);

    static int use_big_lds = -1;
    if (use_big_lds < 0) {
        hipError_t e = hipFuncSetAttribute((const void*)k_outf,
            hipFuncAttributeMaxDynamicSharedMemorySize, (int)SMEM_OUT);
        use_big_lds = (e == hipSuccess) ? 1 : 0;
    }

    k_prep<<<544, 256, 0, stream>>>(x, Wa, Wb, wbb, Wc, wcb, wab16, t1, t2);
    k_projrank<<<512, 256, 0, stream>>>(x, wab16, t1, t2, h, t2s, idxs, pidx);
    k_chunkscan<<<cB * cNC, 128, 0, stream>>>(t2s, idxs, h, EpL, GnL, eps_l, gns_l,
                                              chE, chG, chEs, chGs);
    if (use_big_lds) {
        k_outf<<<256, 256, SMEM_OUT, stream>>>(t1, t2s, pidx, EpL, GnL, eps_l, gns_l,
                                               chE, chG, chEs, chGs, bias, out);
    } else {
        k_offsets<<<cB * 2, 1024, 0, stream>>>(chE, chG, chEs, chGs, ofE, ofG, ofEs, ofGs);
        k_out<<<cNB / 4, 256, 0, stream>>>(t1, t2s, pidx, EpL, GnL, eps_l, gns_l,
                                           ofE, ofG, ofEs, ofGs, bias, out);
    }
}

// Round 10
// 127.102 us; speedup vs baseline: 1.1942x; 1.0966x over previous
//
#include <hip/hip_runtime.h>
#include <hip/hip_bf16.h>

// Problem constants
constexpr int cB = 4;
constexpr int cN = 4096;
constexpr int cD = 512;
constexpr int cK = 64;
constexpr int cNB = cB * cN;       // 16384 rows
constexpr int cNP = cN + 1;        // 4097 prefix rows
constexpr int cCS = 16;            // chunk size for scans
constexpr int cNC = cN / cCS;      // 256 chunks per batch
constexpr int cNC1 = cNC + 1;      // 257

typedef unsigned short u16;
typedef unsigned int u32;
typedef unsigned long long u64;
typedef __bf16 bf16x8 __attribute__((ext_vector_type(8)));
typedef float f32x4 __attribute__((ext_vector_type(4)));

// ---- workspace layout (in floats) ----
constexpr size_t OFF_H    = 0;                                  // cNB*cK
constexpr size_t OFF_T1   = OFF_H    + (size_t)cNB * cK;        // cNB
constexpr size_t OFF_T2   = OFF_T1   + cNB;                     // cNB
constexpr size_t OFF_T2S  = OFF_T2   + cNB;                     // cNB (sorted)
constexpr size_t OFF_IDX  = OFF_T2S  + cNB;                     // cNB (int)
constexpr size_t OFF_P    = OFF_IDX  + cNB;                     // cNB (int) split point per row
constexpr size_t OFF_EPL  = OFF_P    + cNB;                     // cB*cNP*cK
constexpr size_t OFF_GNL  = OFF_EPL  + (size_t)cB * cNP * cK;   // cB*cNP*cK
constexpr size_t OFF_EPS  = OFF_GNL  + (size_t)cB * cNP * cK;   // cB*cNP
constexpr size_t OFF_GNS  = OFF_EPS  + (size_t)cB * cNP;        // cB*cNP
constexpr size_t OFF_CHE  = OFF_GNS  + (size_t)cB * cNP;        // cB*cNC*cK
constexpr size_t OFF_CHG  = OFF_CHE  + (size_t)cB * cNC * cK;
constexpr size_t OFF_CHES = OFF_CHG  + (size_t)cB * cNC * cK;   // cB*cNC
constexpr size_t OFF_CHGS = OFF_CHES + (size_t)cB * cNC;
constexpr size_t OFF_OFE  = OFF_CHGS + (size_t)cB * cNC;        // cB*cNC1*cK (fallback only)
constexpr size_t OFF_OFG  = OFF_OFE  + (size_t)cB * cNC1 * cK;
constexpr size_t OFF_OFES = OFF_OFG  + (size_t)cB * cNC1 * cK;  // cB*cNC1
constexpr size_t OFF_OFGS = OFF_OFES + (size_t)cB * cNC1;
constexpr size_t OFF_WB16 = OFF_OFGS + (size_t)cB * cNC1;       // cK*cD u16

__device__ __forceinline__ u16 f2bf(float f) {
    unsigned u = __float_as_uint(f);
    u += 0x7fffu + ((u >> 16) & 1u);   // RNE
    return (u16)(u >> 16);
}
__device__ __forceinline__ u32 pk2(float a, float b) {
    return (u32)f2bf(a) | ((u32)f2bf(b) << 16);
}
// monotone float -> sortable uint (ascending)
__device__ __forceinline__ u32 f2sort(float f) {
    u32 b = __float_as_uint(f);
    u32 mask = (u32)((int)b >> 31);
    return b ^ (mask | 0x80000000u);
}

// ---------------------------------------------------------------------------
// k_prep (544 blocks): blocks <512: one pass over x -> exact f32 t1/t2 via
// in-block fold of Wa with Wb/Wc. Blocks >=512: Wa -> wab16 (bf16 B operand).
// ---------------------------------------------------------------------------
__global__ __launch_bounds__(256) void k_prep(
    const float* __restrict__ x, const float* __restrict__ Wa,
    const float* __restrict__ Wb, const float* __restrict__ wbb,
    const float* __restrict__ Wc, const float* __restrict__ wcb,
    u16* __restrict__ wab16, float* __restrict__ t1, float* __restrict__ t2)
{
    __shared__ float wabL[cD], wacL[cD];
    int t = threadIdx.x;
    if (blockIdx.x >= 512) {           // wprep slice: 32 blocks x 256 x 4 elems
        int i4 = (((int)blockIdx.x - 512) * 256 + t) * 4;
        float4 v = *(const float4*)(Wa + i4);
        uint2 p = {pk2(v.x, v.y), pk2(v.z, v.w)};
        *(uint2*)(wab16 + i4) = p;
        return;
    }
    float s1a = 0.f, s2a = 0.f, s1b = 0.f, s2b = 0.f;
#pragma unroll 8
    for (int k = 0; k < cK; ++k) {
        float wbk = Wb[k], wck = Wc[k];
        float wa1 = Wa[k * cD + t];
        float wa2 = Wa[k * cD + t + 256];
        s1a += wa1 * wbk; s2a += wa1 * wck;
        s1b += wa2 * wbk; s2b += wa2 * wck;
    }
    wabL[t] = s1a; wacL[t] = s2a; wabL[t + 256] = s1b; wacL[t + 256] = s2b;
    __syncthreads();

    int w = t >> 6, lane = t & 63;
    int d1 = lane * 4, d2 = 256 + lane * 4;
    float4 wbA = *(const float4*)&wabL[d1], wbB = *(const float4*)&wabL[d2];
    float4 wcA = *(const float4*)&wacL[d1], wcB = *(const float4*)&wacL[d2];
    float wbbv = wbb[0], wcbv = wcb[0];
#pragma unroll 2
    for (int rr = 0; rr < 8; ++rr) {
        int row = blockIdx.x * 32 + w * 8 + rr;
        const float* xp = x + (size_t)row * cD;
        float4 a  = *(const float4*)(xp + d1);
        float4 bq = *(const float4*)(xp + d2);
        float p1 = a.x*wbA.x + a.y*wbA.y + a.z*wbA.z + a.w*wbA.w
                 + bq.x*wbB.x + bq.y*wbB.y + bq.z*wbB.z + bq.w*wbB.w;
        float p2 = a.x*wcA.x + a.y*wcA.y + a.z*wcA.z + a.w*wcA.w
                 + bq.x*wcB.x + bq.y*wcB.y + bq.z*wcB.z + bq.w*wcB.w;
#pragma unroll
        for (int off = 32; off > 0; off >>= 1) {
            p1 += __shfl_down(p1, off, 64);
            p2 += __shfl_down(p2, off, 64);
        }
        if (lane == 0) { t1[row] = p1 + wbbv; t2[row] = p2 + wcbv; }
    }
}

// ---------------------------------------------------------------------------
// k_projrank (512 blocks): blocks <256 do the bf16-MFMA GEMM tile (64 rows)
// with direct global->register fragments (zero LDS, zero barriers, A from x
// f32 RNE-converted in-register, B from L1-hot wab16). Blocks >=256 do the
// brute-force rank (u64 composite keys staged in 32 KB LDS) with the fused
// split-point count. NOTE (R9 lesson): keep rank LDS-heavy/VALU-light --
// the co-resident GEMM waves saturate VALU (pk2), while rank's broadcast
// ds_reads overlap the GEMM's VMEM waits. Balanced per-CU pipes beat
// per-block instruction minimization.
// ---------------------------------------------------------------------------
__global__ __launch_bounds__(256) void k_projrank(
    const float* __restrict__ x, const u16* __restrict__ wab16,
    const float* __restrict__ t1, const float* __restrict__ t2,
    float* __restrict__ h, float* __restrict__ t2s, int* __restrict__ idxs,
    int* __restrict__ pidx)
{
    __shared__ __align__(16) u64 shbuf[4096 + 256];   // rank: keys (32KB) + part (2KB)
    int t = threadIdx.x;
    if (blockIdx.x < 256) {
        int rowbase = blockIdx.x * 64;
        int w = t >> 6, lane = t & 63, m = lane & 15, quad = lane >> 4;
        const float* xg = x + (size_t)(rowbase + w * 16 + m) * cD + quad * 8;
        const u16* wg = wab16 + (size_t)m * cD + quad * 8;

        f32x4 acc[4] = {{0.f,0.f,0.f,0.f},{0.f,0.f,0.f,0.f},
                        {0.f,0.f,0.f,0.f},{0.f,0.f,0.f,0.f}};
#pragma unroll 4
        for (int s = 0; s < 16; ++s) {
            float4 xa  = *(const float4*)(xg + s * 32);
            float4 xb2 = *(const float4*)(xg + s * 32 + 4);
            uint4 xv = {pk2(xa.x, xa.y), pk2(xa.z, xa.w),
                        pk2(xb2.x, xb2.y), pk2(xb2.z, xb2.w)};
            bf16x8 av;
            __builtin_memcpy(&av, &xv, 16);
#pragma unroll
            for (int g = 0; g < 4; ++g) {
                uint4 wv = *(const uint4*)(wg + (size_t)g * 16 * cD + s * 32);
                bf16x8 bv;
                __builtin_memcpy(&bv, &wv, 16);
                acc[g] = __builtin_amdgcn_mfma_f32_16x16x32_bf16(av, bv, acc[g], 0, 0, 0);
            }
        }
#pragma unroll
        for (int g = 0; g < 4; ++g) {
#pragma unroll
            for (int r4 = 0; r4 < 4; ++r4) {
                int row = w * 16 + quad * 4 + r4;
                h[(size_t)(rowbase + row) * cK + g * 16 + m] = acc[g][r4];
            }
        }
    } else {
        u64* keys = shbuf;
        int* part = (int*)(shbuf + 4096);   // 512 ints
        int rb = blockIdx.x - 256;
        int b = rb >> 6;
        int rowgrp = rb & 63;
        for (int i = t; i < cN; i += 256)
            keys[i] = ((u64)f2sort(t2[b * cN + i]) << 32) | (u32)i;
        __syncthreads();
        int lane = t & 63, subset = t >> 6;
        int myrow = rowgrp * 64 + lane;
        u64 mykey = keys[myrow];
        u32 pk_hi = f2sort(-t1[(size_t)b * cN + myrow]);  // p-threshold hi word
        int s0 = subset * 1024;
        int cnt = 0, cnt2 = 0;
#pragma unroll 8
        for (int kk = 0; kk < 1024; ++kk) {
            u64 kv = keys[s0 + kk];
            cnt  += (kv < mykey) ? 1 : 0;
            cnt2 += ((u32)(kv >> 32) < pk_hi) ? 1 : 0;
        }
        part[subset * 64 + lane] = cnt;
        part[256 + subset * 64 + lane] = cnt2;
        __syncthreads();
        if (t < 64) {
            int jj = rowgrp * 64 + t;
            int rank = part[t] + part[64 + t] + part[128 + t] + part[192 + t];
            int pc   = part[256 + t] + part[320 + t] + part[384 + t] + part[448 + t];
            t2s[b * cN + rank] = t2[b * cN + jj];
            idxs[b * cN + rank] = jj;
            pidx[b * cN + jj] = pc;
        }
    }
}

// ---------------------------------------------------------------------------
// k_chunkscan: 1024 blocks x 128 thr per (batch, chunk-of-16). The 16 h-rows
// are gathered ONCE into 4 KB LDS (wave w loads rows w*8..w*8+8); wave 0
// then does the E (suffix) scan, wave 1 the G (prefix) scan.
// ---------------------------------------------------------------------------
__global__ __launch_bounds__(128) void k_chunkscan(
    const float* __restrict__ t2s, const int* __restrict__ idxs,
    const float* __restrict__ h,
    float* __restrict__ EpL, float* __restrict__ GnL,
    float* __restrict__ eps_l, float* __restrict__ gns_l,
    float* __restrict__ chE, float* __restrict__ chG,
    float* __restrict__ chEs, float* __restrict__ chGs)
{
    __shared__ float hs[cCS][cK];      // 4 KB
    int t = threadIdx.x;
    int lane = t & 63, w = t >> 6;     // w in {0,1}
    int unit = blockIdx.x;
    int c = unit & (cNC - 1);
    int b = unit >> 8;
    int base = b * cN + c * cCS;
    size_t rowbase = ((size_t)b * cNP + c * cCS) * cK;
    int sbase = b * cNP + c * cCS;
    float M2 = t2s[b * cN + cN - 1];
    int   idxv = (lane < 8) ? idxs[base + w * 8 + lane] : 0;
    float t2v  = (lane < cCS) ? t2s[base + lane] : 0.f;

    // each wave gathers 8 h-rows into LDS
#pragma unroll
    for (int ii = 0; ii < 8; ++ii) {
        int j = __shfl(idxv, ii, 64);
        hs[w * 8 + ii][lane] = h[((size_t)b * cN + j) * cK + lane];
    }
    float slope = w ? 0.2f : 1.0f;
    float ev[cCS];
#pragma unroll
    for (int i = 0; i < cCS; ++i)
        ev[i] = __expf(slope * (__shfl(t2v, i, 64) - M2));
    __syncthreads();

    if (w == 0) {
        if (c == cNC - 1) {
            EpL[((size_t)b * cNP + cN) * cK + lane] = 0.f;
            if (lane == 0) eps_l[b * cNP + cN] = 0.f;
        }
        float acc = 0.f, accs = 0.f;
#pragma unroll
        for (int i = cCS - 1; i >= 0; --i) {
            acc += ev[i] * hs[i][lane]; accs += ev[i];
            EpL[rowbase + (size_t)i * cK + lane] = acc;
            if (lane == 0) eps_l[sbase + i] = accs;
        }
        chE[((size_t)b * cNC + c) * cK + lane] = acc;
        if (lane == 0) chEs[b * cNC + c] = accs;
    } else {
        if (c == cNC - 1) {
            GnL[((size_t)b * cNP + cN) * cK + lane] = 0.f;
            if (lane == 0) gns_l[b * cNP + cN] = 0.f;
        }
        float acc = 0.f, accs = 0.f;
#pragma unroll
        for (int i = 0; i < cCS; ++i) {
            GnL[rowbase + (size_t)i * cK + lane] = acc;
            if (lane == 0) gns_l[sbase + i] = accs;
            acc += ev[i] * hs[i][lane]; accs += ev[i];
        }
        chG[((size_t)b * cNC + c) * cK + lane] = acc;
        if (lane == 0) chGs[b * cNC + c] = accs;
    }
}

// ---------------------------------------------------------------------------
// k_outf: 256 blocks x 256 thr x 64 rows. Per-block prelude rebuilds the
// batch's offset tables in 135 KB dynamic LDS from chE/chG (replaces the
// k_offsets kernel + boundary). Main loop: 16 rows/wave, gather + combine.
// ---------------------------------------------------------------------------
constexpr unsigned SMEM_OUT = 134664;
__global__ __launch_bounds__(256, 1) void k_outf(
    const float* __restrict__ t1, const float* __restrict__ t2s,
    const int* __restrict__ pidx,
    const float* __restrict__ EpL, const float* __restrict__ GnL,
    const float* __restrict__ eps_l, const float* __restrict__ gns_l,
    const float* __restrict__ chE, const float* __restrict__ chG,
    const float* __restrict__ chEs, const float* __restrict__ chGs,
    const float* __restrict__ bias, float* __restrict__ out)
{
    extern __shared__ char sm[];
    float (*ofEl)[64] = (float(*)[64])(sm);                 // 257*64
    float (*ofGl)[64] = (float(*)[64])(sm + 65792);         // 257*64
    float* ofEsL      = (float*)(sm + 131584);              // 257
    float* ofGsL      = (float*)(sm + 132612);              // 257
    float (*wsum)[64] = (float(*)[64])(sm + 133640);        // 4*64

    int t = threadIdx.x, lane = t & 63, w = t >> 6;
    int blk = blockIdx.x;
    int b = blk >> 6;
    const float* chEb = chE + (size_t)b * cNC * cK;
    const float* chGb = chG + (size_t)b * cNC * cK;
    int c0 = w * 64;

    // ---- E suffix scan (vector) + scalar scans on waves 0/1 ----
    {
        float cv[64]; float s = 0.f;
#pragma unroll
        for (int i = 0; i < 64; ++i) { cv[i] = chEb[(size_t)(c0 + i) * cK + lane]; s += cv[i]; }
        wsum[w][lane] = s;
        if (w == 0) {
            float e0 = chEs[b*cNC + lane*4+0], e1 = chEs[b*cNC + lane*4+1];
            float e2 = chEs[b*cNC + lane*4+2], e3 = chEs[b*cNC + lane*4+3];
            float p = e0+e1+e2+e3, s2 = p;
#pragma unroll
            for (int off = 1; off < 64; off <<= 1) {
                float tv = __shfl_down(s2, off, 64);
                if (lane + off < 64) s2 += tv;
            }
            float excl = s2 - p;                  // sum over lanes > lane
            ofEsL[lane*4+0] = excl + e1 + e2 + e3;
            ofEsL[lane*4+1] = excl + e2 + e3;
            ofEsL[lane*4+2] = excl + e3;
            ofEsL[lane*4+3] = excl;
            if (lane == 0) ofEsL[cNC] = 0.f;
        } else if (w == 1) {
            float e0 = chGs[b*cNC + lane*4+0], e1 = chGs[b*cNC + lane*4+1];
            float e2 = chGs[b*cNC + lane*4+2], e3 = chGs[b*cNC + lane*4+3];
            float p = e0+e1+e2+e3, s2 = p;
#pragma unroll
            for (int off = 1; off < 64; off <<= 1) {
                float tv = __shfl_up(s2, off, 64);
                if (lane >= off) s2 += tv;
            }
            float excl = s2 - p;                  // sum over lanes < lane
            ofGsL[lane*4+0] = excl;
            ofGsL[lane*4+1] = excl + e0;
            ofGsL[lane*4+2] = excl + e0 + e1;
            ofGsL[lane*4+3] = excl + e0 + e1 + e2;
            if (lane == 63) ofGsL[cNC] = s2;
        }
        __syncthreads();
        float base = 0.f;
        for (int w2 = w + 1; w2 < 4; ++w2) base += wsum[w2][lane];
        float run = base;
#pragma unroll
        for (int i = 63; i >= 0; --i) { ofEl[c0 + i][lane] = run; run += cv[i]; }
        if (w == 0) ofEl[cNC][lane] = 0.f;
    }
    __syncthreads();    // wsum reuse guard (base reads done)
    // ---- G prefix scan (vector) ----
    {
        float cv[64]; float s = 0.f;
#pragma unroll
        for (int i = 0; i < 64; ++i) { cv[i] = chGb[(size_t)(c0 + i) * cK + lane]; s += cv[i]; }
        wsum[w][lane] = s;
        __syncthreads();
        float base = 0.f;
        for (int w2 = 0; w2 < w; ++w2) base += wsum[w2][lane];
        float run = base;
#pragma unroll
        for (int i = 0; i < 64; ++i) { ofGl[c0 + i][lane] = run; run += cv[i]; }
        if (w == 3) ofGl[cNC][lane] = run;
    }
    __syncthreads();

    // ---- main: 64 rows/block, 16 rows/wave ----
    float bv = bias[lane];
    float M2 = t2s[(size_t)b * cN + cN - 1];
    int r0 = blk * 64 + w * 16;
    const float* epsb = eps_l + (size_t)b * cNP;
    const float* gnsb = gns_l + (size_t)b * cNP;
#pragma unroll 8
    for (int i = 0; i < 16; ++i) {
        int r = r0 + i;
        float T1 = t1[r];
        float smax = T1 + M2;
        float m = fmaxf(smax, 0.2f * smax);      // leaky_relu(smax) = row max
        float A  = __expf(smax - m);
        float Cc = __expf(0.2f * smax - m);
        int p = pidx[r];
        int c = p >> 4;
        size_t pr = ((size_t)b * cNP + p) * cK + lane;
        float num = A * (EpL[pr] + ofEl[c][lane]) + Cc * (GnL[pr] + ofGl[c][lane]);
        float den = A * (epsb[p] + ofEsL[c]) + Cc * (gnsb[p] + ofGsL[c]);
        out[(size_t)r * cK + lane] = num / den + bv;
    }
}

// ---------------------------------------------------------------------------
// Fallback pair (only if the 135 KB LDS attribute is unavailable).
// ---------------------------------------------------------------------------
__global__ __launch_bounds__(1024) void k_offsets(
    const float* __restrict__ chE, const float* __restrict__ chG,
    const float* __restrict__ chEs, const float* __restrict__ chGs,
    float* __restrict__ ofE, float* __restrict__ ofG,
    float* __restrict__ ofEs, float* __restrict__ ofGs)
{
    __shared__ float wsum[16][64];
    int t = threadIdx.x;
    int lane = t & 63, w = t >> 6;
    int dir = blockIdx.x & 1;
    int b = blockIdx.x >> 1;
    const float* ch = dir ? chG : chE;
    float* of = dir ? ofG : ofE;
    int c0 = w * 16;

    float cv[16];
    float s = 0.f;
#pragma unroll
    for (int i = 0; i < 16; ++i) {
        cv[i] = ch[((size_t)b * cNC + c0 + i) * cK + lane];
        s += cv[i];
    }
    wsum[w][lane] = s;
    __syncthreads();
    float base = 0.f;
    if (dir == 0) { for (int w2 = w + 1; w2 < 16; ++w2) base += wsum[w2][lane]; }
    else          { for (int w2 = 0; w2 < w; ++w2) base += wsum[w2][lane]; }

    if (dir == 0) {
        float run = base;
#pragma unroll
        for (int i = 15; i >= 0; --i) {
            of[((size_t)b * cNC1 + c0 + i) * cK + lane] = run;
            run += cv[i];
        }
        if (w == 0) of[((size_t)b * cNC1 + cNC) * cK + lane] = 0.f;
    } else {
        float run = base;
#pragma unroll
        for (int i = 0; i < 16; ++i) {
            of[((size_t)b * cNC1 + c0 + i) * cK + lane] = run;
            run += cv[i];
        }
        if (w == 15) of[((size_t)b * cNC1 + cNC) * cK + lane] = run;
    }

    if (w == 0) {
        const float* chs = dir ? chGs : chEs;
        float* ofs = dir ? ofGs : ofEs;
        float e0 = chs[b * cNC + lane * 4 + 0];
        float e1 = chs[b * cNC + lane * 4 + 1];
        float e2 = chs[b * cNC + lane * 4 + 2];
        float e3 = chs[b * cNC + lane * 4 + 3];
        float p = e0 + e1 + e2 + e3;
        if (dir == 0) {
            float s2 = p;
#pragma unroll
            for (int off = 1; off < 64; off <<= 1) {
                float tv = __shfl_down(s2, off, 64);
                if (lane + off < 64) s2 += tv;
            }
            float excl = s2 - p;
            ofs[b * cNC1 + lane * 4 + 0] = excl + e1 + e2 + e3;
            ofs[b * cNC1 + lane * 4 + 1] = excl + e2 + e3;
            ofs[b * cNC1 + lane * 4 + 2] = excl + e3;
            ofs[b * cNC1 + lane * 4 + 3] = excl;
            if (lane == 0) ofs[b * cNC1 + cNC] = 0.f;
        } else {
            float s2 = p;
#pragma unroll
            for (int off = 1; off < 64; off <<= 1) {
                float tv = __shfl_up(s2, off, 64);
                if (lane >= off) s2 += tv;
            }
            float excl = s2 - p;
            ofs[b * cNC1 + lane * 4 + 0] = excl;
            ofs[b * cNC1 + lane * 4 + 1] = excl + e0;
            ofs[b * cNC1 + lane * 4 + 2] = excl + e0 + e1;
            ofs[b * cNC1 + lane * 4 + 3] = excl + e0 + e1 + e2;
            if (lane == 63) ofs[b * cNC1 + cNC] = s2;
        }
    }
}

__global__ __launch_bounds__(256) void k_out(
    const float* __restrict__ t1, const float* __restrict__ t2s,
    const int* __restrict__ pidx,
    const float* __restrict__ EpL, const float* __restrict__ GnL,
    const float* __restrict__ eps_l, const float* __restrict__ gns_l,
    const float* __restrict__ ofE, const float* __restrict__ ofG,
    const float* __restrict__ ofEs, const float* __restrict__ ofGs,
    const float* __restrict__ bias, float* __restrict__ out)
{
    int tid = threadIdx.x;
    int lane = tid & 63;
    int r = blockIdx.x * 4 + (tid >> 6);
    int b = r >> 12;
    float T1 = t1[r];
    float M2 = t2s[b * cN + cN - 1];
    float smax = T1 + M2;
    float m = fmaxf(smax, 0.2f * smax);
    float A  = __expf(smax - m);
    float Cc = __expf(0.2f * smax - m);
    int p = pidx[r];
    int c = p >> 4;
    size_t pr = ((size_t)b * cNP + p) * cK + lane;
    size_t cr = ((size_t)b * cNC1 + c) * cK + lane;
    float num = A * (EpL[pr] + ofE[cr]) + Cc * (GnL[pr] + ofG[cr]);
    float den = A * (eps_l[(size_t)b * cNP + p] + ofEs[b * cNC1 + c])
              + Cc * (gns_l[(size_t)b * cNP + p] + ofGs[b * cNC1 + c]);
    out[(size_t)r * cK + lane] = num / den + bias[lane];
}

// ---------------------------------------------------------------------------
extern "C" void kernel_launch(void* const* d_in, const int* in_sizes, int n_in,
                              void* d_out, int out_size, void* d_ws, size_t ws_size,
                              hipStream_t stream)
{
    const float* x    = (const float*)d_in[0];
    const float* Wa   = (const float*)d_in[1];
    const float* Wb   = (const float*)d_in[2];
    const float* wbb  = (const float*)d_in[3];
    const float* Wc   = (const float*)d_in[4];
    const float* wcb  = (const float*)d_in[5];
    const float* bias = (const float*)d_in[6];
    float* out = (float*)d_out;

    float* ws = (float*)d_ws;
    float* h     = ws + OFF_H;
    float* t1    = ws + OFF_T1;
    float* t2    = ws + OFF_T2;
    float* t2s   = ws + OFF_T2S;
    int*   idxs  = (int*)(ws + OFF_IDX);
    int*   pidx  = (int*)(ws + OFF_P);
    float* EpL   = ws + OFF_EPL;
    float* GnL   = ws + OFF_GNL;
    float* eps_l = ws + OFF_EPS;
    float* gns_l = ws + OFF_GNS;
    float* chE   = ws + OFF_CHE;
    float* chG   = ws + OFF_CHG;
    float* chEs  = ws + OFF_CHES;
    float* chGs  = ws + OFF_CHGS;
    float* ofE   = ws + OFF_OFE;
    float* ofG   = ws + OFF_OFG;
    float* ofEs  = ws + OFF_OFES;
    float* ofGs  = ws + OFF_OFGS;
    u16*   wab16 = (u16*)(ws + OFF_WB16);

    static int use_big_lds = -1;
    if (use_big_lds < 0) {
        hipError_t e = hipFuncSetAttribute((const void*)k_outf,
            hipFuncAttributeMaxDynamicSharedMemorySize, (int)SMEM_OUT);
        use_big_lds = (e == hipSuccess) ? 1 : 0;
    }

    k_prep<<<544, 256, 0, stream>>>(x, Wa, Wb, wbb, Wc, wcb, wab16, t1, t2);
    k_projrank<<<512, 256, 0, stream>>>(x, wab16, t1, t2, h, t2s, idxs, pidx);
    k_chunkscan<<<cB * cNC, 128, 0, stream>>>(t2s, idxs, h, EpL, GnL, eps_l, gns_l,
                                              chE, chG, chEs, chGs);
    if (use_big_lds) {
        k_outf<<<256, 256, SMEM_OUT, stream>>>(t1, t2s, pidx, EpL, GnL, eps_l, gns_l,
                                               chE, chG, chEs, chGs, bias, out);
    } else {
        k_offsets<<<cB * 2, 1024, 0, stream>>>(chE, chG, chEs, chGs, ofE, ofG, ofEs, ofGs);
        k_out<<<cNB / 4, 256, 0, stream>>>(t1, t2s, pidx, EpL, GnL, eps_l, gns_l,
                                           ofE, ofG, ofEs, ofGs, bias, out);
    }
}